// Round 1
// baseline (22422.981 us; speedup 1.0000x reference)
//
#include <hip/hip_runtime.h>

// ---------------- problem constants ----------------
#define P_NLAT  181
#define P_NLON  360
#define P_V     78
#define P_NGRID (P_NLAT * P_NLON)   // 65160
#define P_B     2
#define P_NMESH 10242
#define P_NEDGE 163840
#define P_ND    256                 // NODE_D
#define P_ED    64                  // EDGE_D
#define P_HID   512
#define P_NLAYERS 16

typedef __bf16 bf16x8 __attribute__((ext_vector_type(8)));
typedef unsigned short u16x8 __attribute__((ext_vector_type(8)));
typedef float f32x4 __attribute__((ext_vector_type(4)));

__device__ __forceinline__ unsigned short f2bf(float f) {
  union { float f; unsigned u; } x; x.f = f;
  unsigned r = x.u + 0x7FFFu + ((x.u >> 16) & 1u);   // RNE
  return (unsigned short)(r >> 16);
}

// ---------------- GEMM argument block ----------------
struct GArgs {
  // A operand
  int amode;                       // 0=direct, 1=edge gather [e|x[src]|x[dst]], 2=row-index gather
  const unsigned short* A; long lda; long a_bstride;
  const unsigned short* e16; long e_bstride;
  const unsigned short* x16; long x_bstride;
  const int* srcI; const int* dstI;
  const int* gidx; int gr_off; int gr_per_b; int gsrc_rows_per_b;   // amode 2
  int M, K;                        // K == Kpad (multiple of 64)
  // B operand: Wt is [Npad][Kpad] bf16, row stride = K
  const unsigned short* Wt;
  // epilogue
  const float* bias; int Nreal; int relu;
  unsigned short* out16; long ldo16; long o16_bstride; long dup16;
  float* out32; long ldo32; long o32_bstride; long dup32;
  const float* resid; long r_bstride;          // indexed with ldo32
  float* agg; long agg_bstride; const int* aggDst;  // fused segment-sum (atomicAdd)
};

#define BM   128
#define BK   64
#define LDSK 72   // +8 bf16 pad -> 144B row stride -> only 2-way LDS conflicts (free)

template<int BN, int WM, int WN>
__global__ void __launch_bounds__(256) gemm_k(GArgs g) {
  constexpr int MI = WM / 16, NJ = WN / 16;
  constexpr int WPN = BN / WN;                  // waves along N
  __shared__ unsigned short As[BM * LDSK];
  __shared__ unsigned short Bs[BN * LDSK];

  const int tid  = threadIdx.x;
  const int lane = tid & 63, wid = tid >> 6;
  const int wm = (wid / WPN) * WM, wn = (wid % WPN) * WN;
  const int bm = blockIdx.x * BM;
  const int bn = blockIdx.y * BN;
  const int z  = blockIdx.z;

  const unsigned short* Ad  = g.A   ? g.A   + (long)z * g.a_bstride : (const unsigned short*)0;
  const unsigned short* e16 = g.e16 ? g.e16 + (long)z * g.e_bstride : (const unsigned short*)0;
  const unsigned short* x16 = g.x16 ? g.x16 + (long)z * g.x_bstride : (const unsigned short*)0;

  f32x4 acc[MI][NJ];
  #pragma unroll
  for (int i = 0; i < MI; ++i) {
    #pragma unroll
    for (int j = 0; j < NJ; ++j) { f32x4 zv = {0.f, 0.f, 0.f, 0.f}; acc[i][j] = zv; }
  }

  const int nKt = g.K / BK;
  for (int kt = 0; kt < nKt; ++kt) {
    const int k0 = kt * BK;
    // ---- stage A tile (BM x BK), 16B per thread-iter, row-gather aware ----
    #pragma unroll
    for (int it = 0; it < (BM * BK / 8) / 256; ++it) {
      int v = tid + it * 256;
      int r = v >> 3, kc = (v & 7) << 3;
      int row = bm + r; if (row >= g.M) row = g.M - 1;    // clamp; stores are masked
      int kk = k0 + kc;
      const unsigned short* s;
      if (g.amode == 0) {
        s = Ad + (long)row * g.lda + kk;
      } else if (g.amode == 1) {
        if (kk < P_ED)              s = e16 + (long)row * P_ED + kk;
        else if (kk < P_ED + P_ND)  s = x16 + (long)g.srcI[row] * P_ND + (kk - P_ED);
        else                        s = x16 + (long)g.dstI[row] * P_ND + (kk - P_ED - P_ND);
      } else {
        int gr  = g.gr_off + row;
        int b   = gr / g.gr_per_b;
        int loc = gr - b * g.gr_per_b;
        s = x16 + ((long)b * g.gsrc_rows_per_b + g.gidx[loc]) * g.lda + kk;
      }
      *(u16x8*)&As[r * LDSK + kc] = *(const u16x8*)s;
    }
    // ---- stage B tile (BN x BK) from pre-transposed Wt ----
    #pragma unroll
    for (int it = 0; it < (BN * BK / 8) / 256; ++it) {
      int v = tid + it * 256;
      int n = v >> 3, kc = (v & 7) << 3;
      *(u16x8*)&Bs[n * LDSK + kc] = *(const u16x8*)(g.Wt + (long)(bn + n) * g.K + k0 + kc);
    }
    __syncthreads();
    // ---- MFMA over the two K=32 sub-steps ----
    #pragma unroll
    for (int ko = 0; ko < 2; ++ko) {
      bf16x8 af[MI], bfr[NJ];
      #pragma unroll
      for (int i = 0; i < MI; ++i) {
        u16x8 t = *(const u16x8*)&As[(wm + i * 16 + (lane & 15)) * LDSK + ko * 32 + (lane >> 4) * 8];
        af[i] = __builtin_bit_cast(bf16x8, t);
      }
      #pragma unroll
      for (int j = 0; j < NJ; ++j) {
        u16x8 t = *(const u16x8*)&Bs[(wn + j * 16 + (lane & 15)) * LDSK + ko * 32 + (lane >> 4) * 8];
        bfr[j] = __builtin_bit_cast(bf16x8, t);
      }
      #pragma unroll
      for (int i = 0; i < MI; ++i) {
        #pragma unroll
        for (int j = 0; j < NJ; ++j)
          acc[i][j] = __builtin_amdgcn_mfma_f32_16x16x32_bf16(af[i], bfr[j], acc[i][j], 0, 0, 0);
      }
    }
    __syncthreads();
  }

  // ---- epilogue: bias (+resid) (+relu) -> {bf16, fp32} (+dup) (+atomic segsum) ----
  unsigned short* o16 = g.out16 ? g.out16 + (long)z * g.o16_bstride : (unsigned short*)0;
  float* o32 = g.out32 ? g.out32 + (long)z * g.o32_bstride : (float*)0;
  const float* res = g.resid ? g.resid + (long)z * g.r_bstride : (const float*)0;
  float* agg = g.agg ? g.agg + (long)z * g.agg_bstride : (float*)0;
  const int q = lane >> 4, cc = lane & 15;
  #pragma unroll
  for (int i = 0; i < MI; ++i) {
    #pragma unroll
    for (int j = 0; j < NJ; ++j) {
      #pragma unroll
      for (int r = 0; r < 4; ++r) {
        int row = bm + wm + i * 16 + q * 4 + r;   // C/D map: col=lane&15, row=quad*4+reg
        int col = bn + wn + j * 16 + cc;
        if (row >= g.M || col >= g.Nreal) continue;
        float v = acc[i][j][r] + g.bias[col];
        if (res) v += res[(long)row * g.ldo32 + col];
        if (g.relu && v < 0.f) v = 0.f;
        if (o32) {
          long idx = (long)row * g.ldo32 + col;
          o32[idx] = v; if (g.dup32) o32[idx + g.dup32] = v;
        }
        if (o16) {
          long idx = (long)row * g.ldo16 + col;
          unsigned short h = f2bf(v);
          o16[idx] = h; if (g.dup16) o16[idx + g.dup16] = h;
        }
        if (agg) atomicAdd(agg + (long)g.aggDst[row] * P_ED + col, v);
      }
    }
  }
}

// ---------------- prep kernels ----------------
// transpose + bf16-convert + pad weights: W[K][N] fp32 -> Wt[Npad][Kpad] bf16; grid.z = layer
__global__ void wt_conv(const float* W, unsigned short* Wt, int K, int N, int Kpad, int Npad) {
  long t = (long)blockIdx.x * 256 + threadIdx.x;
  long tot = (long)Npad * Kpad;
  if (t >= tot) return;
  int n = (int)(t / Kpad), k = (int)(t - (long)n * Kpad);
  const float* Wl = W + (long)blockIdx.z * K * N;
  unsigned short* Wtl = Wt + (long)blockIdx.z * tot;
  float v = (n < N && k < K) ? Wl[(long)k * N + n] : 0.f;
  Wtl[t] = f2bf(v);
}

// encoder input: [x_cur[g2m] | x_prev[g2m] | mesh_feats] padded to 192, bf16
__global__ void build_enc_in(const float* xc, const float* xp, const float* mesh,
                             const int* g2m, unsigned short* out) {
  long t = (long)blockIdx.x * 256 + threadIdx.x;
  const long tot = (long)P_B * P_NMESH * 192;
  if (t >= tot) return;
  int k = (int)(t % 192); long r = t / 192;
  int m = (int)(r % P_NMESH); int b = (int)(r / P_NMESH);
  float v = 0.f;
  if (k < P_V)            v = xc[((long)b * P_NGRID + g2m[m]) * P_V + k];
  else if (k < 2 * P_V)   v = xp[((long)b * P_NGRID + g2m[m]) * P_V + (k - P_V)];
  else if (k < 2 * P_V + 7) v = mesh[m * 7 + (k - 2 * P_V)];
  out[t] = f2bf(v);
}

__global__ void build_rawpad(const float* raw, unsigned short* out) {
  long t = (long)blockIdx.x * 256 + threadIdx.x;
  const long tot = (long)P_NEDGE * 64;
  if (t >= tot) return;
  int k = (int)(t & 63); long r = t >> 6;
  out[t] = f2bf(k < 4 ? raw[r * 4 + k] : 0.f);
}

// node MLP input: [x16 (256) | bf16(agg) (64)]
__global__ void build_node_in(const unsigned short* X16, const float* agg, unsigned short* out) {
  long t = (long)blockIdx.x * 256 + threadIdx.x;
  const long tot = (long)P_B * P_NMESH * (P_ND + P_ED);
  if (t >= tot) return;
  int k = (int)(t % (P_ND + P_ED)); long r = t / (P_ND + P_ED);
  out[t] = (k < P_ND) ? X16[r * P_ND + k] : f2bf(agg[r * P_ED + (k - P_ND)]);
}

// ---------------- host launch ----------------
extern "C" void kernel_launch(void* const* d_in, const int* in_sizes, int n_in,
                              void* d_out, int out_size, void* d_ws, size_t ws_size,
                              hipStream_t stream) {
  (void)in_sizes; (void)n_in; (void)out_size;
  const float* x_current  = (const float*)d_in[0];
  const float* x_previous = (const float*)d_in[1];
  const float* mesh_feats = (const float*)d_in[2];
  const float* raw_edge   = (const float*)d_in[3];
  const int*   edge_index = (const int*)d_in[4];
  const int*   g2m        = (const int*)d_in[5];
  const int*   m2g        = (const int*)d_in[6];
  const float* enc_w1 = (const float*)d_in[7];
  const float* enc_b1 = (const float*)d_in[8];
  const float* enc_w2 = (const float*)d_in[9];
  const float* enc_b2 = (const float*)d_in[10];
  const float* eme_w1 = (const float*)d_in[11];
  const float* eme_b1 = (const float*)d_in[12];
  const float* eme_w2 = (const float*)d_in[13];
  const float* eme_b2 = (const float*)d_in[14];
  const float* pe_w1 = (const float*)d_in[15];
  const float* pe_b1 = (const float*)d_in[16];
  const float* pe_w2 = (const float*)d_in[17];
  const float* pe_b2 = (const float*)d_in[18];
  const float* pn_w1 = (const float*)d_in[19];
  const float* pn_b1 = (const float*)d_in[20];
  const float* pn_w2 = (const float*)d_in[21];
  const float* pn_b2 = (const float*)d_in[22];
  const float* dec_w1 = (const float*)d_in[23];
  const float* dec_b1 = (const float*)d_in[24];
  const float* dec_w2 = (const float*)d_in[25];
  const float* dec_b2 = (const float*)d_in[26];
  const int* srcI = edge_index;
  const int* dstI = edge_index + P_NEDGE;
  float* out = (float*)d_out;

  char* wsb = (char*)d_ws; size_t off = 0;
  auto alloc = [&](size_t bytes) -> void* {
    off = (off + 255) & ~(size_t)255;
    void* p = wsb + off; off += bytes; return p;
  };
  auto au16 = [&](long n) { return (unsigned short*)alloc((size_t)n * 2); };
  auto af32 = [&](long n) { return (float*)alloc((size_t)n * 4); };

  unsigned short* enc_w1t = au16(512L * 192);
  unsigned short* enc_w2t = au16(256L * 512);
  unsigned short* eme_w1t = au16(64L * 64);
  unsigned short* eme_w2t = au16(64L * 64);
  unsigned short* pe_w1t  = au16(16L * 512 * 576);
  unsigned short* pe_w2t  = au16(16L * 64 * 512);
  unsigned short* pn_w1t  = au16(16L * 512 * 320);
  unsigned short* pn_w2t  = au16(16L * 256 * 512);
  unsigned short* dec_w1t = au16(512L * 256);
  unsigned short* dec_w2t = au16(128L * 512);
  unsigned short* ENCIN   = au16((long)P_B * P_NMESH * 192);
  unsigned short* RAWPAD  = au16((long)P_NEDGE * 64);
  float*          X32     = af32((long)P_B * P_NMESH * P_ND);
  unsigned short* X16     = au16((long)P_B * P_NMESH * P_ND);
  float*          E32     = af32((long)P_B * P_NEDGE * P_ED);
  unsigned short* E16     = au16((long)P_B * P_NEDGE * P_ED);
  float*          AGG     = af32((long)P_B * P_NMESH * P_ED);
  unsigned short* NIN     = au16((long)P_B * P_NMESH * (P_ND + P_ED));

  // hidden-buffer chunking chosen from remaining workspace (deterministic per ws_size)
  size_t rem = (ws_size > off + 512) ? ws_size - off - 512 : 0;
  int EC = 4, DC = 2;
  long hrows = 2L * (P_NEDGE / EC);            // 81920 rows of 512
  if ((size_t)hrows * 512 * 2 > rem) { EC = 8; DC = 4; hrows = 2L * (P_NEDGE / EC); }
  unsigned short* HBUF = au16(hrows * 512);

  auto run128 = [&](const GArgs& a, int Npad, int zdim) {
    dim3 grid((a.M + BM - 1) / BM, Npad / 128, zdim);
    gemm_k<128, 64, 64><<<grid, dim3(256), 0, stream>>>(a);
  };
  auto run64 = [&](const GArgs& a, int zdim) {
    dim3 grid((a.M + BM - 1) / BM, 1, zdim);
    gemm_k<64, 32, 64><<<grid, dim3(256), 0, stream>>>(a);
  };
  auto convw = [&](const float* W, unsigned short* Wt, int K, int N, int Kp, int Np, int L) {
    long tot = (long)Np * Kp;
    wt_conv<<<dim3((unsigned)((tot + 255) / 256), 1, L), dim3(256), 0, stream>>>(W, Wt, K, N, Kp, Np);
  };

  // ---- weight conversion/transposition ----
  convw(enc_w1, enc_w1t, 163, 512, 192, 512, 1);
  convw(enc_w2, enc_w2t, 512, 256, 512, 256, 1);
  convw(eme_w1, eme_w1t, 4, 64, 64, 64, 1);
  convw(eme_w2, eme_w2t, 64, 64, 64, 64, 1);
  convw(pe_w1, pe_w1t, 576, 512, 576, 512, 16);
  convw(pe_w2, pe_w2t, 512, 64, 512, 64, 16);
  convw(pn_w1, pn_w1t, 320, 512, 320, 512, 16);
  convw(pn_w2, pn_w2t, 512, 256, 512, 256, 16);
  convw(dec_w1, dec_w1t, 256, 512, 256, 512, 1);
  convw(dec_w2, dec_w2t, 512, 78, 512, 128, 1);

  // ---- encoder input + edge-embed input ----
  { long tot = (long)P_B * P_NMESH * 192;
    build_enc_in<<<dim3((unsigned)((tot + 255) / 256)), dim3(256), 0, stream>>>(x_current, x_previous, mesh_feats, g2m, ENCIN); }
  { long tot = (long)P_NEDGE * 64;
    build_rawpad<<<dim3((unsigned)((tot + 255) / 256)), dim3(256), 0, stream>>>(raw_edge, RAWPAD); }

  // ---- encoder MLP ----
  { GArgs a{}; a.amode = 0; a.A = ENCIN; a.lda = 192; a.M = P_B * P_NMESH; a.K = 192;
    a.Wt = enc_w1t; a.bias = enc_b1; a.Nreal = 512; a.relu = 1;
    a.out16 = HBUF; a.ldo16 = 512; run128(a, 512, 1); }
  { GArgs a{}; a.amode = 0; a.A = HBUF; a.lda = 512; a.M = P_B * P_NMESH; a.K = 512;
    a.Wt = enc_w2t; a.bias = enc_b2; a.Nreal = 256; a.relu = 0;
    a.out32 = X32; a.ldo32 = 256; a.out16 = X16; a.ldo16 = 256; run128(a, 256, 1); }

  // ---- edge embedder (shared by both batches -> dup write) ----
  { GArgs a{}; a.amode = 0; a.A = RAWPAD; a.lda = 64; a.M = P_NEDGE; a.K = 64;
    a.Wt = eme_w1t; a.bias = eme_b1; a.Nreal = 64; a.relu = 1;
    a.out16 = HBUF; a.ldo16 = 64; run64(a, 1); }
  { GArgs a{}; a.amode = 0; a.A = HBUF; a.lda = 64; a.M = P_NEDGE; a.K = 64;
    a.Wt = eme_w2t; a.bias = eme_b2; a.Nreal = 64; a.relu = 0;
    a.out32 = E32; a.ldo32 = 64; a.dup32 = (long)P_NEDGE * 64;
    a.out16 = E16; a.ldo16 = 64; a.dup16 = (long)P_NEDGE * 64; run64(a, 1); }

  // ---- 16 GNN layers ----
  const long XB = (long)P_NMESH * P_ND;
  const long EB = (long)P_NEDGE * P_ED;
  const long AB = (long)P_NMESH * P_ED;
  const int ecrows = P_NEDGE / EC;
  for (int l = 0; l < P_NLAYERS; ++l) {
    hipMemsetAsync(AGG, 0, (size_t)P_B * P_NMESH * P_ED * 4, stream);
    for (int c = 0; c < EC; ++c) {
      long c0 = (long)c * ecrows;
      // edge MLP1: gather [e | x[src] | x[dst]] -> relu -> HBUF
      GArgs a{}; a.amode = 1;
      a.e16 = E16 + c0 * P_ED; a.e_bstride = EB;
      a.x16 = X16; a.x_bstride = XB;
      a.srcI = srcI + c0; a.dstI = dstI + c0;
      a.M = ecrows; a.K = 576;
      a.Wt = pe_w1t + (long)l * 512 * 576; a.bias = pe_b1 + l * 512; a.Nreal = 512; a.relu = 1;
      a.out16 = HBUF; a.ldo16 = 512; a.o16_bstride = (long)ecrows * 512;
      run128(a, 512, 2);
      // edge MLP2: + residual -> E32/E16, fused segment-sum into AGG
      GArgs b{}; b.amode = 0; b.A = HBUF; b.lda = 512; b.a_bstride = (long)ecrows * 512;
      b.M = ecrows; b.K = 512;
      b.Wt = pe_w2t + (long)l * 64 * 512; b.bias = pe_b2 + l * 64; b.Nreal = 64; b.relu = 0;
      b.resid = E32 + c0 * P_ED; b.r_bstride = EB;
      b.out32 = E32 + c0 * P_ED; b.ldo32 = 64; b.o32_bstride = EB;
      b.out16 = E16 + c0 * P_ED; b.ldo16 = 64; b.o16_bstride = EB;
      b.agg = AGG; b.agg_bstride = AB; b.aggDst = dstI + c0;
      run64(b, 2);
    }
    { long tot = (long)P_B * P_NMESH * (P_ND + P_ED);
      build_node_in<<<dim3((unsigned)((tot + 255) / 256)), dim3(256), 0, stream>>>(X16, AGG, NIN); }
    { GArgs a{}; a.amode = 0; a.A = NIN; a.lda = 320; a.M = P_B * P_NMESH; a.K = 320;
      a.Wt = pn_w1t + (long)l * 512 * 320; a.bias = pn_b1 + l * 512; a.Nreal = 512; a.relu = 1;
      a.out16 = HBUF; a.ldo16 = 512; run128(a, 512, 1); }
    { GArgs a{}; a.amode = 0; a.A = HBUF; a.lda = 512; a.M = P_B * P_NMESH; a.K = 512;
      a.Wt = pn_w2t + (long)l * 256 * 512; a.bias = pn_b2 + l * 256; a.Nreal = 256; a.relu = 0;
      a.resid = X32; a.out32 = X32; a.ldo32 = 256; a.out16 = X16; a.ldo16 = 256;
      run128(a, 256, 1); }
  }

  // ---- decoder (row-index gather over m2g), chunked through HBUF ----
  const int dcrows = (P_B * P_NGRID) / DC;   // 130320 divisible by 2 and 4
  for (int c = 0; c < DC; ++c) {
    int c0 = c * dcrows;
    { GArgs a{}; a.amode = 2; a.x16 = X16; a.lda = P_ND;
      a.gidx = m2g; a.gr_off = c0; a.gr_per_b = P_NGRID; a.gsrc_rows_per_b = P_NMESH;
      a.M = dcrows; a.K = 256;
      a.Wt = dec_w1t; a.bias = dec_b1; a.Nreal = 512; a.relu = 1;
      a.out16 = HBUF; a.ldo16 = 512; run128(a, 512, 1); }
    { GArgs a{}; a.amode = 0; a.A = HBUF; a.lda = 512; a.M = dcrows; a.K = 512;
      a.Wt = dec_w2t; a.bias = dec_b2; a.Nreal = 78; a.relu = 0;
      a.out32 = out + (long)c0 * P_V; a.ldo32 = P_V;
      run128(a, 128, 1); }
  }
}

// Round 2
// 20885.762 us; speedup vs baseline: 1.0736x; 1.0736x over previous
//
#include <hip/hip_runtime.h>

// ---------------- problem constants ----------------
#define P_NLAT  181
#define P_NLON  360
#define P_V     78
#define P_NGRID (P_NLAT * P_NLON)   // 65160
#define P_B     2
#define P_NMESH 10242
#define P_NEDGE 163840
#define P_ND    256
#define P_ED    64
#define P_HID   512
#define P_NLAYERS 16

typedef __bf16 bf16x8 __attribute__((ext_vector_type(8)));
typedef unsigned short u16x8 __attribute__((ext_vector_type(8)));
typedef float f32x4 __attribute__((ext_vector_type(4)));

__device__ __forceinline__ unsigned short f2bf(float f) {
  union { float f; unsigned u; } x; x.f = f;
  unsigned r = x.u + 0x7FFFu + ((x.u >> 16) & 1u);   // RNE
  return (unsigned short)(r >> 16);
}
__device__ __forceinline__ float bf2f(unsigned short h) {
  union { unsigned u; float f; } x; x.u = ((unsigned)h) << 16; return x.f;
}

// async global->LDS, 16B per lane; LDS dest is wave-uniform base + lane*16
__device__ __forceinline__ void gl_lds16(const unsigned short* gp, unsigned short* lp) {
  __builtin_amdgcn_global_load_lds(
      (const __attribute__((address_space(1))) unsigned int*)gp,
      (__attribute__((address_space(3))) unsigned int*)lp, 16, 0, 0);
}

// ---------------- GEMM argument block ----------------
struct GArgs {
  int amode;                       // 0=direct, 2=row-index gather
  const unsigned short* A; long lda; long a_bstride;
  const int* gidx; int gr_off; int gr_per_b; int gsrc_rows_per_b;   // amode 2
  int M, K;                        // K multiple of 64
  const unsigned short* Wt;        // [Npad][K] bf16
  const float* bias; int Nreal; int relu;
  unsigned short* out16; long ldo16; long o16_bstride; long dup16;
  float* out32; long ldo32; long o32_bstride; long dup32;
  const float* resid; long r_bstride;              // fp32 residual, stride ldo32
  const unsigned short* gpA; const int* gpAIdx; long gpA_bstride;  // += gpA[idx[row]*512+col]
  const unsigned short* gpB; const int* gpBIdx; long gpB_bstride;
};

#define BM 128

template<int BN, int WM, int WN>
__global__ void __launch_bounds__(256) gemm_k(GArgs g) {
  constexpr int MI = WM / 16, NJ = WN / 16;
  constexpr int WPN = BN / WN;
  __shared__ unsigned short As[BM * 64];
  __shared__ unsigned short Bs[BN * 64];

  const int tid  = threadIdx.x;
  const int lane = tid & 63, wid = tid >> 6;
  const int wm = (wid / WPN) * WM, wn = (wid % WPN) * WN;
  const int bm = blockIdx.x * BM;
  const int bn = blockIdx.y * BN;
  const int z  = blockIdx.z;

  const unsigned short* Ad = g.A + (long)z * g.a_bstride;

  f32x4 acc[MI][NJ];
  #pragma unroll
  for (int i = 0; i < MI; ++i)
    #pragma unroll
    for (int j = 0; j < NJ; ++j) { f32x4 zv = {0.f, 0.f, 0.f, 0.f}; acc[i][j] = zv; }

  const int nKt = g.K >> 6;
  for (int kt = 0; kt < nKt; ++kt) {
    const int k0 = kt << 6;
    // ---- A tile: swizzled chunk = j ^ (r&7); LDS dest contiguous for global_load_lds ----
    #pragma unroll
    for (int it = 0; it < (BM * 8) / 256; ++it) {
      int v = tid + it * 256;
      int r = v >> 3, j = v & 7;
      int row = bm + r; if (row >= g.M) row = g.M - 1;
      int kk = k0 + ((j ^ (r & 7)) << 3);
      const unsigned short* s;
      if (g.amode == 0) {
        s = Ad + (long)row * g.lda + kk;
      } else {
        int gr = g.gr_off + row;
        int b = gr / g.gr_per_b, loc = gr - b * g.gr_per_b;
        s = g.A + ((long)b * g.gsrc_rows_per_b + g.gidx[loc]) * g.lda + kk;
      }
      gl_lds16(s, &As[v << 3]);
    }
    // ---- B tile ----
    #pragma unroll
    for (int it = 0; it < (BN * 8) / 256; ++it) {
      int v = tid + it * 256;
      int n = v >> 3, j = v & 7;
      gl_lds16(g.Wt + (long)(bn + n) * g.K + k0 + ((j ^ (n & 7)) << 3), &Bs[v << 3]);
    }
    __syncthreads();
    #pragma unroll
    for (int ko = 0; ko < 2; ++ko) {
      bf16x8 af[MI], bfr[NJ];
      #pragma unroll
      for (int i = 0; i < MI; ++i) {
        int ar = wm + i * 16 + (lane & 15);
        int ch = ((ko * 4 + (lane >> 4)) ^ (ar & 7)) << 3;
        u16x8 t = *(const u16x8*)&As[ar * 64 + ch];
        af[i] = __builtin_bit_cast(bf16x8, t);
      }
      #pragma unroll
      for (int j = 0; j < NJ; ++j) {
        int br = wn + j * 16 + (lane & 15);
        int ch = ((ko * 4 + (lane >> 4)) ^ (br & 7)) << 3;
        u16x8 t = *(const u16x8*)&Bs[br * 64 + ch];
        bfr[j] = __builtin_bit_cast(bf16x8, t);
      }
      #pragma unroll
      for (int i = 0; i < MI; ++i)
        #pragma unroll
        for (int j = 0; j < NJ; ++j)
          acc[i][j] = __builtin_amdgcn_mfma_f32_16x16x32_bf16(af[i], bfr[j], acc[i][j], 0, 0, 0);
    }
    __syncthreads();
  }

  // ---- epilogue ----
  unsigned short* o16 = g.out16 ? g.out16 + (long)z * g.o16_bstride : (unsigned short*)0;
  float* o32 = g.out32 ? g.out32 + (long)z * g.o32_bstride : (float*)0;
  const float* res = g.resid ? g.resid + (long)z * g.r_bstride : (const float*)0;
  const unsigned short* gA = g.gpA ? g.gpA + (long)z * g.gpA_bstride : (const unsigned short*)0;
  const unsigned short* gB = g.gpB ? g.gpB + (long)z * g.gpB_bstride : (const unsigned short*)0;
  const int q = lane >> 4, cc = lane & 15;
  #pragma unroll
  for (int i = 0; i < MI; ++i) {
    #pragma unroll
    for (int r = 0; r < 4; ++r) {
      int row = bm + wm + i * 16 + q * 4 + r;
      if (row >= g.M) continue;
      const unsigned short* pa = gA ? gA + (long)g.gpAIdx[row] * 512 : (const unsigned short*)0;
      const unsigned short* pb = gB ? gB + (long)g.gpBIdx[row] * 512 : (const unsigned short*)0;
      const float* rr = res ? res + (long)row * g.ldo32 : (const float*)0;
      #pragma unroll
      for (int j = 0; j < NJ; ++j) {
        int col = bn + wn + j * 16 + cc;
        if (col >= g.Nreal) continue;
        float v = acc[i][j][r];
        if (g.bias) v += g.bias[col];
        if (pa) v += bf2f(pa[col]);
        if (pb) v += bf2f(pb[col]);
        if (rr) v += rr[col];
        if (g.relu && v < 0.f) v = 0.f;
        if (o32) {
          long idx = (long)row * g.ldo32 + col;
          o32[idx] = v; if (g.dup32) o32[idx + g.dup32] = v;
        }
        if (o16) {
          long idx = (long)row * g.ldo16 + col;
          unsigned short h = f2bf(v);
          o16[idx] = h; if (g.dup16) o16[idx + g.dup16] = h;
        }
      }
    }
  }
}

// ---------------- prep kernels ----------------
__global__ void wt_conv(const float* W, unsigned short* Wt, int K, int N, int Kpad, int Npad,
                        int row_off, long lstride) {
  long t = (long)blockIdx.x * 256 + threadIdx.x;
  long tot = (long)Npad * Kpad;
  if (t >= tot) return;
  int n = (int)(t / Kpad), k = (int)(t - (long)n * Kpad);
  const float* Wl = W + (long)blockIdx.z * lstride + (long)row_off * N;
  float v = (n < N && k < K) ? Wl[(long)k * N + n] : 0.f;
  Wt[(long)blockIdx.z * tot + t] = f2bf(v);
}

__global__ void build_enc_in(const float* xc, const float* xp, const float* mesh,
                             const int* g2m, unsigned short* out) {
  long t = (long)blockIdx.x * 256 + threadIdx.x;
  const long tot = (long)P_B * P_NMESH * 192;
  if (t >= tot) return;
  int k = (int)(t % 192); long r = t / 192;
  int m = (int)(r % P_NMESH); int b = (int)(r / P_NMESH);
  float v = 0.f;
  if (k < P_V)              v = xc[((long)b * P_NGRID + g2m[m]) * P_V + k];
  else if (k < 2 * P_V)     v = xp[((long)b * P_NGRID + g2m[m]) * P_V + (k - P_V)];
  else if (k < 2 * P_V + 7) v = mesh[m * 7 + (k - 2 * P_V)];
  out[t] = f2bf(v);
}

// raw edge feats, permuted into dst-sorted order, padded to 64
__global__ void build_rawpad(const float* raw, const int* perm, unsigned short* out) {
  long t = (long)blockIdx.x * 256 + threadIdx.x;
  const long tot = (long)P_NEDGE * 64;
  if (t >= tot) return;
  int k = (int)(t & 63); long r = t >> 6;
  int e = perm[r];
  out[t] = f2bf(k < 4 ? raw[(long)e * 4 + k] : 0.f);
}

// ---------------- CSR build (counting sort by dst) ----------------
__global__ void csr_hist(const int* dst, int* cnt) {
  int e = blockIdx.x * 256 + threadIdx.x;
  if (e < P_NEDGE) atomicAdd(&cnt[dst[e]], 1);
}
__global__ void csr_scan(const int* cnt, int* rowptr) {
  __shared__ int part[1024];
  int t = threadIdx.x;
  const int C = (P_NMESH + 1023) / 1024;
  int base = t * C, s = 0;
  for (int i = 0; i < C; ++i) { int idx = base + i; if (idx < P_NMESH) s += cnt[idx]; }
  part[t] = s; __syncthreads();
  for (int ofs = 1; ofs < 1024; ofs <<= 1) {
    int v = (t >= ofs) ? part[t - ofs] : 0;
    __syncthreads();
    part[t] += v;
    __syncthreads();
  }
  int excl = (t == 0) ? 0 : part[t - 1];
  for (int i = 0; i < C; ++i) {
    int idx = base + i;
    if (idx < P_NMESH) { rowptr[idx] = excl; excl += cnt[idx]; }
  }
  if (t == 1023) rowptr[P_NMESH] = excl;
}
__global__ void csr_scatter(const int* dst, const int* rowptr, int* cursor, int* perm) {
  int e = blockIdx.x * 256 + threadIdx.x;
  if (e < P_NEDGE) {
    int d = dst[e];
    int pos = atomicAdd(&cursor[d], 1);
    perm[rowptr[d] + pos] = e;
  }
}
__global__ void csr_permsd(const int* perm, const int* src, const int* dst, int* srcP, int* dstP) {
  int i = blockIdx.x * 256 + threadIdx.x;
  if (i < P_NEDGE) { int p = perm[i]; srcP[i] = src[p]; dstP[i] = dst[p]; }
}

// contiguous segmented sum over dst-sorted E32 -> bf16 into XN[:, 256:320]
__global__ void seg_reduce(const float* E32, const int* rowptr, unsigned short* XN) {
  int node = blockIdx.x * 4 + (threadIdx.x >> 6);
  int c = threadIdx.x & 63;
  int b = blockIdx.y;
  if (node >= P_NMESH) return;
  int r0 = rowptr[node], r1 = rowptr[node + 1];
  const float* base = E32 + (long)b * P_NEDGE * 64;
  float s = 0.f;
  for (int r = r0; r < r1; ++r) s += base[(long)r * 64 + c];
  XN[((long)b * P_NMESH + node) * 320 + 256 + c] = f2bf(s);
}

// ---------------- host launch ----------------
extern "C" void kernel_launch(void* const* d_in, const int* in_sizes, int n_in,
                              void* d_out, int out_size, void* d_ws, size_t ws_size,
                              hipStream_t stream) {
  (void)in_sizes; (void)n_in; (void)out_size;
  const float* x_current  = (const float*)d_in[0];
  const float* x_previous = (const float*)d_in[1];
  const float* mesh_feats = (const float*)d_in[2];
  const float* raw_edge   = (const float*)d_in[3];
  const int*   edge_index = (const int*)d_in[4];
  const int*   g2m        = (const int*)d_in[5];
  const int*   m2g        = (const int*)d_in[6];
  const float* enc_w1 = (const float*)d_in[7];
  const float* enc_b1 = (const float*)d_in[8];
  const float* enc_w2 = (const float*)d_in[9];
  const float* enc_b2 = (const float*)d_in[10];
  const float* eme_w1 = (const float*)d_in[11];
  const float* eme_b1 = (const float*)d_in[12];
  const float* eme_w2 = (const float*)d_in[13];
  const float* eme_b2 = (const float*)d_in[14];
  const float* pe_w1 = (const float*)d_in[15];
  const float* pe_b1 = (const float*)d_in[16];
  const float* pe_w2 = (const float*)d_in[17];
  const float* pe_b2 = (const float*)d_in[18];
  const float* pn_w1 = (const float*)d_in[19];
  const float* pn_b1 = (const float*)d_in[20];
  const float* pn_w2 = (const float*)d_in[21];
  const float* pn_b2 = (const float*)d_in[22];
  const float* dec_w1 = (const float*)d_in[23];
  const float* dec_b1 = (const float*)d_in[24];
  const float* dec_w2 = (const float*)d_in[25];
  const float* dec_b2 = (const float*)d_in[26];
  const int* srcI = edge_index;
  const int* dstI = edge_index + P_NEDGE;
  float* out = (float*)d_out;

  char* wsb = (char*)d_ws; size_t off = 0;
  auto alloc = [&](size_t bytes) -> void* {
    off = (off + 255) & ~(size_t)255;
    void* p = wsb + off; off += bytes; return p;
  };
  auto au16 = [&](long n) { return (unsigned short*)alloc((size_t)n * 2); };
  auto af32 = [&](long n) { return (float*)alloc((size_t)n * 4); };
  auto ai32 = [&](long n) { return (int*)alloc((size_t)n * 4); };

  // weights (bf16, transposed [N][K])
  unsigned short* enc_w1t  = au16(512L * 192);
  unsigned short* enc_w2t  = au16(256L * 512);
  unsigned short* eme_w1t  = au16(64L * 64);
  unsigned short* eme_w2t  = au16(64L * 64);
  unsigned short* pe_w1e_t = au16(16L * 512 * 64);
  unsigned short* pe_w1s_t = au16(16L * 512 * 256);
  unsigned short* pe_w1d_t = au16(16L * 512 * 256);
  unsigned short* pe_w2t   = au16(16L * 64 * 512);
  unsigned short* pn_w1t   = au16(16L * 512 * 320);
  unsigned short* pn_w2t   = au16(16L * 256 * 512);
  unsigned short* dec_w1t  = au16(512L * 256);
  unsigned short* dec_w2t  = au16(128L * 512);
  // CSR
  int* cnt    = ai32(P_NMESH);
  int* cursor = ai32(P_NMESH);
  int* rowptr = ai32(P_NMESH + 1);
  int* perm   = ai32(P_NEDGE);
  int* srcP   = ai32(P_NEDGE);
  int* dstP   = ai32(P_NEDGE);
  // state
  float*          X32 = af32((long)P_B * P_NMESH * P_ND);          // fp32 node master
  unsigned short* XN  = au16((long)P_B * P_NMESH * 320);           // [x bf16 | agg bf16]
  float*          E32 = af32((long)P_B * P_NEDGE * P_ED);          // fp32 edge master
  unsigned short* E16 = au16((long)P_B * P_NEDGE * P_ED);
  // overlay region: {ENCIN, RAWPAD} (pre-layer) vs {PS, PD} (per-layer)
  size_t encin_b  = ((size_t)P_B * P_NMESH * 192 * 2 + 255) & ~(size_t)255;
  size_t rawpad_b = ((size_t)P_NEDGE * 64 * 2 + 255) & ~(size_t)255;
  size_t ps_b     = ((size_t)P_B * P_NMESH * 512 * 2 + 255) & ~(size_t)255;
  size_t reg1_b   = encin_b + rawpad_b; if (2 * ps_b > reg1_b) reg1_b = 2 * ps_b;
  char* region1 = (char*)alloc(reg1_b);
  unsigned short* ENCIN  = (unsigned short*)region1;
  unsigned short* RAWPAD = (unsigned short*)(region1 + encin_b);
  unsigned short* PS     = (unsigned short*)region1;
  unsigned short* PD     = (unsigned short*)(region1 + ps_b);

  // hidden buffer, chunk factor from remaining ws
  size_t rem = (ws_size > off + 1024) ? ws_size - off - 1024 : 0;
  int EC = 4, DC = 2;
  if ((size_t)(2L * (P_NEDGE / EC) * 512 * 2) > rem) { EC = 8; DC = 4; }
  unsigned short* HBUF = au16(2L * (P_NEDGE / EC) * 512);

  auto run128 = [&](const GArgs& a, int Npad, int zdim) {
    dim3 grid((a.M + BM - 1) / BM, Npad / 128, zdim);
    gemm_k<128, 64, 64><<<grid, dim3(256), 0, stream>>>(a);
  };
  auto run64 = [&](const GArgs& a, int zdim) {
    dim3 grid((a.M + BM - 1) / BM, 1, zdim);
    gemm_k<64, 32, 64><<<grid, dim3(256), 0, stream>>>(a);
  };
  auto convw = [&](const float* W, unsigned short* Wt, int K, int N, int Kp, int Np,
                   int row_off, long lstride, int L) {
    long tot = (long)Np * Kp;
    wt_conv<<<dim3((unsigned)((tot + 255) / 256), 1, L), dim3(256), 0, stream>>>(
        W, Wt, K, N, Kp, Np, row_off, lstride);
  };

  // ---- CSR build (once per call, inside graph) ----
  hipMemsetAsync(cnt, 0, P_NMESH * 4, stream);
  hipMemsetAsync(cursor, 0, P_NMESH * 4, stream);
  csr_hist<<<dim3(P_NEDGE / 256), dim3(256), 0, stream>>>(dstI, cnt);
  csr_scan<<<dim3(1), dim3(1024), 0, stream>>>(cnt, rowptr);
  csr_scatter<<<dim3(P_NEDGE / 256), dim3(256), 0, stream>>>(dstI, rowptr, cursor, perm);
  csr_permsd<<<dim3(P_NEDGE / 256), dim3(256), 0, stream>>>(perm, srcI, dstI, srcP, dstP);

  // ---- weight conversion ----
  convw(enc_w1, enc_w1t, 163, 512, 192, 512, 0, 163L * 512, 1);
  convw(enc_w2, enc_w2t, 512, 256, 512, 256, 0, 512L * 256, 1);
  convw(eme_w1, eme_w1t, 4, 64, 64, 64, 0, 4L * 64, 1);
  convw(eme_w2, eme_w2t, 64, 64, 64, 64, 0, 64L * 64, 1);
  convw(pe_w1, pe_w1e_t, 64, 512, 64, 512, 0, 576L * 512, 16);
  convw(pe_w1, pe_w1s_t, 256, 512, 256, 512, 64, 576L * 512, 16);
  convw(pe_w1, pe_w1d_t, 256, 512, 256, 512, 320, 576L * 512, 16);
  convw(pe_w2, pe_w2t, 512, 64, 512, 64, 0, 512L * 64, 16);
  convw(pn_w1, pn_w1t, 320, 512, 320, 512, 0, 320L * 512, 16);
  convw(pn_w2, pn_w2t, 512, 256, 512, 256, 0, 512L * 256, 16);
  convw(dec_w1, dec_w1t, 256, 512, 256, 512, 0, 256L * 512, 1);
  convw(dec_w2, dec_w2t, 512, 78, 512, 128, 0, 512L * 78, 1);

  // ---- inputs ----
  { long tot = (long)P_B * P_NMESH * 192;
    build_enc_in<<<dim3((unsigned)((tot + 255) / 256)), dim3(256), 0, stream>>>(
        x_current, x_previous, mesh_feats, g2m, ENCIN); }
  { long tot = (long)P_NEDGE * 64;
    build_rawpad<<<dim3((unsigned)((tot + 255) / 256)), dim3(256), 0, stream>>>(
        raw_edge, perm, RAWPAD); }

  // ---- encoder ----
  { GArgs a{}; a.amode = 0; a.A = ENCIN; a.lda = 192; a.M = P_B * P_NMESH; a.K = 192;
    a.Wt = enc_w1t; a.bias = enc_b1; a.Nreal = 512; a.relu = 1;
    a.out16 = HBUF; a.ldo16 = 512; run128(a, 512, 1); }
  { GArgs a{}; a.amode = 0; a.A = HBUF; a.lda = 512; a.M = P_B * P_NMESH; a.K = 512;
    a.Wt = enc_w2t; a.bias = enc_b2; a.Nreal = 256; a.relu = 0;
    a.out32 = X32; a.ldo32 = 256; a.out16 = XN; a.ldo16 = 320; run128(a, 256, 1); }

  // ---- edge embedder (sorted edge order; dup to batch 1) ----
  { GArgs a{}; a.amode = 0; a.A = RAWPAD; a.lda = 64; a.M = P_NEDGE; a.K = 64;
    a.Wt = eme_w1t; a.bias = eme_b1; a.Nreal = 64; a.relu = 1;
    a.out16 = HBUF; a.ldo16 = 64; run64(a, 1); }
  { GArgs a{}; a.amode = 0; a.A = HBUF; a.lda = 64; a.M = P_NEDGE; a.K = 64;
    a.Wt = eme_w2t; a.bias = eme_b2; a.Nreal = 64; a.relu = 0;
    a.out32 = E32; a.ldo32 = 64; a.dup32 = (long)P_NEDGE * 64;
    a.out16 = E16; a.ldo16 = 64; a.dup16 = (long)P_NEDGE * 64; run64(a, 1); }

  // ---- 16 GNN layers ----
  const long XB = (long)P_NMESH * 512;   // PS/PD batch stride
  const long EB = (long)P_NEDGE * P_ED;
  const int  ecrows = P_NEDGE / EC;
  for (int l = 0; l < P_NLAYERS; ++l) {
    // per-node projections Ps = x@W1s, Pd = x@W1d  (batch folded into M)
    { GArgs a{}; a.amode = 0; a.A = XN; a.lda = 320; a.M = P_B * P_NMESH; a.K = 256;
      a.Wt = pe_w1s_t + (long)l * 512 * 256; a.Nreal = 512; a.relu = 0;
      a.out16 = PS; a.ldo16 = 512; run128(a, 512, 1); }
    { GArgs a{}; a.amode = 0; a.A = XN; a.lda = 320; a.M = P_B * P_NMESH; a.K = 256;
      a.Wt = pe_w1d_t + (long)l * 512 * 256; a.Nreal = 512; a.relu = 0;
      a.out16 = PD; a.ldo16 = 512; run128(a, 512, 1); }
    for (int c = 0; c < EC; ++c) {
      long c0 = (long)c * ecrows;
      // edge MLP1: h = relu(e@W1e + Ps[src] + Pd[dst] + b1)
      { GArgs a{}; a.amode = 0; a.A = E16 + c0 * P_ED; a.lda = P_ED; a.a_bstride = EB;
        a.M = ecrows; a.K = 64;
        a.Wt = pe_w1e_t + (long)l * 512 * 64; a.bias = pe_b1 + l * 512; a.Nreal = 512; a.relu = 1;
        a.gpA = PS; a.gpAIdx = srcP + c0; a.gpA_bstride = XB;
        a.gpB = PD; a.gpBIdx = dstP + c0; a.gpB_bstride = XB;
        a.out16 = HBUF; a.ldo16 = 512; a.o16_bstride = (long)ecrows * 512;
        run128(a, 512, 2); }
      // edge MLP2 + residual -> E32/E16 (dst-sorted order)
      { GArgs b{}; b.amode = 0; b.A = HBUF; b.lda = 512; b.a_bstride = (long)ecrows * 512;
        b.M = ecrows; b.K = 512;
        b.Wt = pe_w2t + (long)l * 64 * 512; b.bias = pe_b2 + l * 64; b.Nreal = 64; b.relu = 0;
        b.resid = E32 + c0 * P_ED; b.r_bstride = EB;
        b.out32 = E32 + c0 * P_ED; b.ldo32 = 64; b.o32_bstride = EB;
        b.out16 = E16 + c0 * P_ED; b.ldo16 = 64; b.o16_bstride = EB;
        run64(b, 2); }
    }
    // contiguous segment sum -> XN[:,256:320]
    seg_reduce<<<dim3((P_NMESH + 3) / 4, P_B), dim3(256), 0, stream>>>(E32, rowptr, XN);
    // node MLPs
    { GArgs a{}; a.amode = 0; a.A = XN; a.lda = 320; a.M = P_B * P_NMESH; a.K = 320;
      a.Wt = pn_w1t + (long)l * 512 * 320; a.bias = pn_b1 + l * 512; a.Nreal = 512; a.relu = 1;
      a.out16 = HBUF; a.ldo16 = 512; run128(a, 512, 1); }
    { GArgs a{}; a.amode = 0; a.A = HBUF; a.lda = 512; a.M = P_B * P_NMESH; a.K = 512;
      a.Wt = pn_w2t + (long)l * 256 * 512; a.bias = pn_b2 + l * 256; a.Nreal = 256; a.relu = 0;
      a.resid = X32; a.out32 = X32; a.ldo32 = 256; a.out16 = XN; a.ldo16 = 320;
      run128(a, 256, 1); }
  }

  // ---- decoder ----
  const int dcrows = (P_B * P_NGRID) / DC;
  for (int c = 0; c < DC; ++c) {
    int c0 = c * dcrows;
    { GArgs a{}; a.amode = 2; a.A = XN; a.lda = 320;
      a.gidx = m2g; a.gr_off = c0; a.gr_per_b = P_NGRID; a.gsrc_rows_per_b = P_NMESH;
      a.M = dcrows; a.K = 256;
      a.Wt = dec_w1t; a.bias = dec_b1; a.Nreal = 512; a.relu = 1;
      a.out16 = HBUF; a.ldo16 = 512; run128(a, 512, 1); }
    { GArgs a{}; a.amode = 0; a.A = HBUF; a.lda = 512; a.M = dcrows; a.K = 512;
      a.Wt = dec_w2t; a.bias = dec_b2; a.Nreal = 78; a.relu = 0;
      a.out32 = out + (long)c0 * P_V; a.ldo32 = P_V;
      run128(a, 128, 1); }
  }
}

// Round 3
// 5593.189 us; speedup vs baseline: 4.0090x; 3.7341x over previous
//
#include <hip/hip_runtime.h>

// ---------------- problem constants ----------------
#define P_NLAT  181
#define P_NLON  360
#define P_V     78
#define P_NGRID (P_NLAT * P_NLON)   // 65160
#define P_B     2
#define P_NMESH 10242
#define P_NEDGE 163840
#define P_ND    256
#define P_ED    64
#define P_HID   512
#define P_NLAYERS 16

typedef __bf16 bf16x8 __attribute__((ext_vector_type(8)));
typedef unsigned short u16x8 __attribute__((ext_vector_type(8)));
typedef float f32x4 __attribute__((ext_vector_type(4)));

__device__ __forceinline__ unsigned short f2bf(float f) {
  union { float f; unsigned u; } x; x.f = f;
  unsigned r = x.u + 0x7FFFu + ((x.u >> 16) & 1u);   // RNE
  return (unsigned short)(r >> 16);
}
__device__ __forceinline__ float bf2f(unsigned short h) {
  union { unsigned u; float f; } x; x.u = ((unsigned)h) << 16; return x.f;
}

// async global->LDS, 16B per lane; LDS dest is wave-uniform base + lane*16
__device__ __forceinline__ void gl_lds16(const unsigned short* gp, unsigned short* lp) {
  __builtin_amdgcn_global_load_lds(
      (const __attribute__((address_space(1))) unsigned int*)gp,
      (__attribute__((address_space(3))) unsigned int*)lp, 16, 0, 0);
}

// ---------------- generic GEMM (unchanged workhorse) ----------------
struct GArgs {
  int amode;                       // 0=direct, 2=row-index gather
  const unsigned short* A; long lda; long a_bstride;
  const int* gidx; int gr_off; int gr_per_b; int gsrc_rows_per_b;
  int M, K;
  const unsigned short* Wt;        // [Npad][K] bf16
  const float* bias; int Nreal; int relu;
  unsigned short* out16; long ldo16; long o16_bstride; long dup16;
  float* out32; long ldo32; long o32_bstride; long dup32;
  const float* resid; long r_bstride;
};

#define BM 128

template<int BN, int WM, int WN>
__global__ void __launch_bounds__(256) gemm_k(GArgs g) {
  constexpr int MI = WM / 16, NJ = WN / 16;
  constexpr int WPN = BN / WN;
  __shared__ unsigned short As[BM * 64];
  __shared__ unsigned short Bs[BN * 64];

  const int tid  = threadIdx.x;
  const int lane = tid & 63, wid = tid >> 6;
  const int wm = (wid / WPN) * WM, wn = (wid % WPN) * WN;
  const int bm = blockIdx.x * BM;
  const int bn = blockIdx.y * BN;
  const int z  = blockIdx.z;

  const unsigned short* Ad = g.A + (long)z * g.a_bstride;

  f32x4 acc[MI][NJ];
  #pragma unroll
  for (int i = 0; i < MI; ++i)
    #pragma unroll
    for (int j = 0; j < NJ; ++j) { f32x4 zv = {0.f, 0.f, 0.f, 0.f}; acc[i][j] = zv; }

  const int nKt = g.K >> 6;
  for (int kt = 0; kt < nKt; ++kt) {
    const int k0 = kt << 6;
    #pragma unroll
    for (int it = 0; it < (BM * 8) / 256; ++it) {
      int v = tid + it * 256;
      int r = v >> 3, j = v & 7;
      int row = bm + r; if (row >= g.M) row = g.M - 1;
      int kk = k0 + ((j ^ (r & 7)) << 3);
      const unsigned short* s;
      if (g.amode == 0) {
        s = Ad + (long)row * g.lda + kk;
      } else {
        int gr = g.gr_off + row;
        int b = gr / g.gr_per_b, loc = gr - b * g.gr_per_b;
        s = g.A + ((long)b * g.gsrc_rows_per_b + g.gidx[loc]) * g.lda + kk;
      }
      gl_lds16(s, &As[v << 3]);
    }
    #pragma unroll
    for (int it = 0; it < (BN * 8) / 256; ++it) {
      int v = tid + it * 256;
      int n = v >> 3, j = v & 7;
      gl_lds16(g.Wt + (long)(bn + n) * g.K + k0 + ((j ^ (n & 7)) << 3), &Bs[v << 3]);
    }
    __syncthreads();
    #pragma unroll
    for (int ko = 0; ko < 2; ++ko) {
      bf16x8 af[MI], bfr[NJ];
      #pragma unroll
      for (int i = 0; i < MI; ++i) {
        int ar = wm + i * 16 + (lane & 15);
        int ch = ((ko * 4 + (lane >> 4)) ^ (ar & 7)) << 3;
        u16x8 t = *(const u16x8*)&As[ar * 64 + ch];
        af[i] = __builtin_bit_cast(bf16x8, t);
      }
      #pragma unroll
      for (int j = 0; j < NJ; ++j) {
        int br = wn + j * 16 + (lane & 15);
        int ch = ((ko * 4 + (lane >> 4)) ^ (br & 7)) << 3;
        u16x8 t = *(const u16x8*)&Bs[br * 64 + ch];
        bfr[j] = __builtin_bit_cast(bf16x8, t);
      }
      #pragma unroll
      for (int i = 0; i < MI; ++i)
        #pragma unroll
        for (int j = 0; j < NJ; ++j)
          acc[i][j] = __builtin_amdgcn_mfma_f32_16x16x32_bf16(af[i], bfr[j], acc[i][j], 0, 0, 0);
    }
    __syncthreads();
  }

  unsigned short* o16 = g.out16 ? g.out16 + (long)z * g.o16_bstride : (unsigned short*)0;
  float* o32 = g.out32 ? g.out32 + (long)z * g.o32_bstride : (float*)0;
  const float* res = g.resid ? g.resid + (long)z * g.r_bstride : (const float*)0;
  const int q = lane >> 4, cc = lane & 15;
  #pragma unroll
  for (int i = 0; i < MI; ++i) {
    #pragma unroll
    for (int r = 0; r < 4; ++r) {
      int row = bm + wm + i * 16 + q * 4 + r;
      if (row >= g.M) continue;
      const float* rr = res ? res + (long)row * g.ldo32 : (const float*)0;
      #pragma unroll
      for (int j = 0; j < NJ; ++j) {
        int col = bn + wn + j * 16 + cc;
        if (col >= g.Nreal) continue;
        float v = acc[i][j][r];
        if (g.bias) v += g.bias[col];
        if (rr) v += rr[col];
        if (g.relu && v < 0.f) v = 0.f;
        if (o32) {
          long idx = (long)row * g.ldo32 + col;
          o32[idx] = v; if (g.dup32) o32[idx + g.dup32] = v;
        }
        if (o16) {
          long idx = (long)row * g.ldo16 + col;
          unsigned short h = f2bf(v);
          o16[idx] = h; if (g.dup16) o16[idx + g.dup16] = h;
        }
      }
    }
  }
}

// ---------------- fused edge layer: E' = E + MLP2(relu(E@W1e + Ps[src] + Pd[dst] + b1)) ----------------
struct FEArgs {
  unsigned short* E16;             // in/out, dst-sorted, per-batch stride NEDGE*64
  float* E32;                      // in/out residual master
  const unsigned short* PSPD;      // [B*NMESH][1024]: cols 0..511 = Ps, 512..1023 = Pd
  const int* srcP; const int* dstP;
  const unsigned short* W1t;       // [512][64]
  const unsigned short* W2t;       // [64][512]
  const float* b1; const float* b2;
};

__global__ void __launch_bounds__(256) fused_edge(FEArgs g) {
  __shared__ unsigned short As[64 * 64];      // e tile (bf16), swizzled           8 KB
  __shared__ float Hs32[64 * 132];            // raw h chunk fp32 (pad +4)        33.8 KB
  __shared__ unsigned short U1[64 * 136];     // B1s [128][64] / Hs16 [64][136]   17 KB
  __shared__ unsigned short B2s[64 * 128];    // W2 chunk [64 n][128 k]           16 KB

  const int tid = threadIdx.x, lane = tid & 63, wid = tid >> 6;
  const int q = lane >> 4, cc = lane & 15;
  const int z = blockIdx.y;
  const long gr0 = (long)blockIdx.x * 64;
  const long EB = (long)P_NEDGE * 64;
  unsigned short* E16z = g.E16 + z * EB;
  float* E32z = g.E32 + z * EB;
  const int moff = z * P_NMESH;

  // stage e tile (rows gr0..gr0+63)
  #pragma unroll
  for (int it = 0; it < 2; ++it) {
    int v = tid + it * 256;
    int r = v >> 3, j = v & 7;
    gl_lds16(E16z + (gr0 + r) * 64 + ((j ^ (r & 7)) << 3), &As[v << 3]);
  }

  // GEMM1 tiling: 4 waves as 2x2 of 32x64; GEMM2: 4 waves as 4x1 of 16x64
  const int wm1 = (wid >> 1) * 32, wn1 = (wid & 1) * 64;
  const int wm2 = wid * 16;

  f32x4 acc2[4];
  #pragma unroll
  for (int j = 0; j < 4; ++j) { f32x4 zv = {0.f, 0.f, 0.f, 0.f}; acc2[j] = zv; }

  for (int hc = 0; hc < 4; ++hc) {
    // stage B1s = W1t rows [hc*128 .. +128) into U1, swizzled
    #pragma unroll
    for (int it = 0; it < 4; ++it) {
      int v = tid + it * 256;
      int n = v >> 3, j = v & 7;
      gl_lds16(g.W1t + (long)(hc * 128 + n) * 64 + ((j ^ (n & 7)) << 3), &U1[v << 3]);
    }
    __syncthreads();

    // GEMM1: h_acc(64x128) = e @ W1chunk   (K=64)
    f32x4 acc1[2][4];
    #pragma unroll
    for (int i = 0; i < 2; ++i)
      #pragma unroll
      for (int j = 0; j < 4; ++j) { f32x4 zv = {0.f, 0.f, 0.f, 0.f}; acc1[i][j] = zv; }
    #pragma unroll
    for (int ko = 0; ko < 2; ++ko) {
      bf16x8 af[2], bfr[4];
      #pragma unroll
      for (int i = 0; i < 2; ++i) {
        int ar = wm1 + i * 16 + cc;
        int ch = ((ko * 4 + q) ^ (ar & 7)) << 3;
        u16x8 t = *(const u16x8*)&As[ar * 64 + ch];
        af[i] = __builtin_bit_cast(bf16x8, t);
      }
      #pragma unroll
      for (int j = 0; j < 4; ++j) {
        int n = wn1 + j * 16 + cc;
        int ch = ((ko * 4 + q) ^ (n & 7)) << 3;
        u16x8 t = *(const u16x8*)&U1[n * 64 + ch];
        bfr[j] = __builtin_bit_cast(bf16x8, t);
      }
      #pragma unroll
      for (int i = 0; i < 2; ++i)
        #pragma unroll
        for (int j = 0; j < 4; ++j)
          acc1[i][j] = __builtin_amdgcn_mfma_f32_16x16x32_bf16(af[i], bfr[j], acc1[i][j], 0, 0, 0);
    }
    // spill raw fp32 h to LDS (C-layout scatter; banks 2-way max)
    #pragma unroll
    for (int i = 0; i < 2; ++i)
      #pragma unroll
      for (int j = 0; j < 4; ++j)
        #pragma unroll
        for (int r = 0; r < 4; ++r)
          Hs32[(wm1 + i * 16 + q * 4 + r) * 132 + wn1 + j * 16 + cc] = acc1[i][j][r];
    __syncthreads();

    // pass2: h = relu(raw + b1 + Ps[src] + Pd[dst]) -> bf16 into U1 (A-layout, pad 136)
    #pragma unroll
    for (int it = 0; it < 4; ++it) {
      int v = tid + it * 256;
      int r = v >> 4, c8 = (v & 15) << 3;
      long grow = gr0 + r;
      const unsigned short* ps = g.PSPD + ((long)(moff + g.srcP[grow])) * 1024 + hc * 128 + c8;
      const unsigned short* pd = g.PSPD + ((long)(moff + g.dstP[grow])) * 1024 + 512 + hc * 128 + c8;
      u16x8 psv = *(const u16x8*)ps;
      u16x8 pdv = *(const u16x8*)pd;
      f32x4 ha = *(const f32x4*)&Hs32[r * 132 + c8];
      f32x4 hb = *(const f32x4*)&Hs32[r * 132 + c8 + 4];
      const float* b1p = g.b1 + hc * 128 + c8;
      u16x8 outv;
      #pragma unroll
      for (int e = 0; e < 8; ++e) {
        float x = (e < 4 ? ha[e] : hb[e - 4]) + b1p[e] + bf2f(psv[e]) + bf2f(pdv[e]);
        outv[e] = f2bf(x < 0.f ? 0.f : x);
      }
      *(u16x8*)&U1[r * 136 + c8] = outv;
    }
    // stage B2s = W2t[:, hc*128 .. +128) (safe: prev GEMM2 done per loop-end barrier)
    #pragma unroll
    for (int it = 0; it < 4; ++it) {
      int v = tid + it * 256;
      int n = v >> 4, j = v & 15;
      gl_lds16(g.W2t + (long)n * 512 + hc * 128 + ((j ^ (n & 7)) << 3), &B2s[v << 3]);
    }
    __syncthreads();

    // GEMM2: C(64x64) += h_chunk(64x128) @ W2chunk(128x64)
    #pragma unroll
    for (int ko = 0; ko < 4; ++ko) {
      int ar = wm2 + cc;
      u16x8 ta = *(const u16x8*)&U1[ar * 136 + ko * 32 + q * 8];
      bf16x8 af = __builtin_bit_cast(bf16x8, ta);
      #pragma unroll
      for (int j = 0; j < 4; ++j) {
        int n = j * 16 + cc;
        int ch = ((ko * 4 + q) ^ (n & 7)) << 3;
        u16x8 tb = *(const u16x8*)&B2s[n * 128 + ch];
        bf16x8 bf = __builtin_bit_cast(bf16x8, tb);
        acc2[j] = __builtin_amdgcn_mfma_f32_16x16x32_bf16(af, bf, acc2[j], 0, 0, 0);
      }
    }
    __syncthreads();
  }

  // final epilogue: residual update
  #pragma unroll
  for (int j = 0; j < 4; ++j) {
    #pragma unroll
    for (int r = 0; r < 4; ++r) {
      int row = wm2 + q * 4 + r;
      int col = j * 16 + cc;
      long idx = (gr0 + row) * 64 + col;
      float v = acc2[j][r] + g.b2[col] + E32z[idx];
      E32z[idx] = v;
      E16z[idx] = f2bf(v);
    }
  }
}

// ---------------- prep kernels ----------------
__global__ void wt_conv(const float* W, unsigned short* Wt, int K, int N, int Kpad, int Npad,
                        int row_off, long in_lstride, long out_lstride) {
  long t = (long)blockIdx.x * 256 + threadIdx.x;
  long tot = (long)Npad * Kpad;
  if (t >= tot) return;
  int n = (int)(t / Kpad), k = (int)(t - (long)n * Kpad);
  const float* Wl = W + (long)blockIdx.z * in_lstride + (long)row_off * N;
  float v = (n < N && k < K) ? Wl[(long)k * N + n] : 0.f;
  Wt[(long)blockIdx.z * out_lstride + t] = f2bf(v);
}

__global__ void build_enc_in(const float* xc, const float* xp, const float* mesh,
                             const int* g2m, unsigned short* out) {
  long t = (long)blockIdx.x * 256 + threadIdx.x;
  const long tot = (long)P_B * P_NMESH * 192;
  if (t >= tot) return;
  int k = (int)(t % 192); long r = t / 192;
  int m = (int)(r % P_NMESH); int b = (int)(r / P_NMESH);
  float v = 0.f;
  if (k < P_V)              v = xc[((long)b * P_NGRID + g2m[m]) * P_V + k];
  else if (k < 2 * P_V)     v = xp[((long)b * P_NGRID + g2m[m]) * P_V + (k - P_V)];
  else if (k < 2 * P_V + 7) v = mesh[m * 7 + (k - 2 * P_V)];
  out[t] = f2bf(v);
}

__global__ void build_rawpad(const float* raw, const int* perm, unsigned short* out) {
  long t = (long)blockIdx.x * 256 + threadIdx.x;
  const long tot = (long)P_NEDGE * 64;
  if (t >= tot) return;
  int k = (int)(t & 63); long r = t >> 6;
  int e = perm[r];
  out[t] = f2bf(k < 4 ? raw[(long)e * 4 + k] : 0.f);
}

// ---------------- CSR build (counting sort by dst) ----------------
__global__ void csr_hist(const int* dst, int* cnt) {
  int e = blockIdx.x * 256 + threadIdx.x;
  if (e < P_NEDGE) atomicAdd(&cnt[dst[e]], 1);
}
__global__ void csr_scan(const int* cnt, int* rowptr) {
  __shared__ int part[1024];
  int t = threadIdx.x;
  const int C = (P_NMESH + 1023) / 1024;
  int base = t * C, s = 0;
  for (int i = 0; i < C; ++i) { int idx = base + i; if (idx < P_NMESH) s += cnt[idx]; }
  part[t] = s; __syncthreads();
  for (int ofs = 1; ofs < 1024; ofs <<= 1) {
    int v = (t >= ofs) ? part[t - ofs] : 0;
    __syncthreads();
    part[t] += v;
    __syncthreads();
  }
  int excl = (t == 0) ? 0 : part[t - 1];
  for (int i = 0; i < C; ++i) {
    int idx = base + i;
    if (idx < P_NMESH) { rowptr[idx] = excl; excl += cnt[idx]; }
  }
  if (t == 1023) rowptr[P_NMESH] = excl;
}
__global__ void csr_scatter(const int* dst, const int* rowptr, int* cursor, int* perm) {
  int e = blockIdx.x * 256 + threadIdx.x;
  if (e < P_NEDGE) {
    int d = dst[e];
    int pos = atomicAdd(&cursor[d], 1);
    perm[rowptr[d] + pos] = e;
  }
}
__global__ void csr_permsd(const int* perm, const int* src, const int* dst, int* srcP, int* dstP) {
  int i = blockIdx.x * 256 + threadIdx.x;
  if (i < P_NEDGE) { int p = perm[i]; srcP[i] = src[p]; dstP[i] = dst[p]; }
}

// contiguous segmented sum over dst-sorted E32 -> bf16 into XN[:, 256:320]
__global__ void seg_reduce(const float* E32, const int* rowptr, unsigned short* XN) {
  int node = blockIdx.x * 4 + (threadIdx.x >> 6);
  int c = threadIdx.x & 63;
  int b = blockIdx.y;
  if (node >= P_NMESH) return;
  int r0 = rowptr[node], r1 = rowptr[node + 1];
  const float* base = E32 + (long)b * P_NEDGE * 64;
  float s = 0.f;
  for (int r = r0; r < r1; ++r) s += base[(long)r * 64 + c];
  XN[((long)b * P_NMESH + node) * 320 + 256 + c] = f2bf(s);
}

// ---------------- host launch ----------------
extern "C" void kernel_launch(void* const* d_in, const int* in_sizes, int n_in,
                              void* d_out, int out_size, void* d_ws, size_t ws_size,
                              hipStream_t stream) {
  (void)in_sizes; (void)n_in; (void)out_size;
  const float* x_current  = (const float*)d_in[0];
  const float* x_previous = (const float*)d_in[1];
  const float* mesh_feats = (const float*)d_in[2];
  const float* raw_edge   = (const float*)d_in[3];
  const int*   edge_index = (const int*)d_in[4];
  const int*   g2m        = (const int*)d_in[5];
  const int*   m2g        = (const int*)d_in[6];
  const float* enc_w1 = (const float*)d_in[7];
  const float* enc_b1 = (const float*)d_in[8];
  const float* enc_w2 = (const float*)d_in[9];
  const float* enc_b2 = (const float*)d_in[10];
  const float* eme_w1 = (const float*)d_in[11];
  const float* eme_b1 = (const float*)d_in[12];
  const float* eme_w2 = (const float*)d_in[13];
  const float* eme_b2 = (const float*)d_in[14];
  const float* pe_w1 = (const float*)d_in[15];
  const float* pe_b1 = (const float*)d_in[16];
  const float* pe_w2 = (const float*)d_in[17];
  const float* pe_b2 = (const float*)d_in[18];
  const float* pn_w1 = (const float*)d_in[19];
  const float* pn_b1 = (const float*)d_in[20];
  const float* pn_w2 = (const float*)d_in[21];
  const float* pn_b2 = (const float*)d_in[22];
  const float* dec_w1 = (const float*)d_in[23];
  const float* dec_b1 = (const float*)d_in[24];
  const float* dec_w2 = (const float*)d_in[25];
  const float* dec_b2 = (const float*)d_in[26];
  const int* srcI = edge_index;
  const int* dstI = edge_index + P_NEDGE;
  float* out = (float*)d_out;

  char* wsb = (char*)d_ws; size_t off = 0;
  auto alloc = [&](size_t bytes) -> void* {
    off = (off + 255) & ~(size_t)255;
    void* p = wsb + off; off += bytes; return p;
  };
  auto au16 = [&](long n) { return (unsigned short*)alloc((size_t)n * 2); };
  auto af32 = [&](long n) { return (float*)alloc((size_t)n * 4); };
  auto ai32 = [&](long n) { return (int*)alloc((size_t)n * 4); };

  // weights (bf16, transposed [N][K])
  unsigned short* enc_w1t   = au16(512L * 192);
  unsigned short* enc_w2t   = au16(256L * 512);
  unsigned short* eme_w1t   = au16(64L * 64);
  unsigned short* eme_w2t   = au16(64L * 64);
  unsigned short* pe_w1e_t  = au16(16L * 512 * 64);
  unsigned short* pe_w1sd_t = au16(16L * 1024 * 256);   // [1024][256]: s rows 0..511, d rows 512..1023
  unsigned short* pe_w2t    = au16(16L * 64 * 512);
  unsigned short* pn_w1t    = au16(16L * 512 * 320);
  unsigned short* pn_w2t    = au16(16L * 256 * 512);
  unsigned short* dec_w1t   = au16(512L * 256);
  unsigned short* dec_w2t   = au16(128L * 512);
  // CSR
  int* cnt    = ai32(P_NMESH);
  int* cursor = ai32(P_NMESH);
  int* rowptr = ai32(P_NMESH + 1);
  int* perm   = ai32(P_NEDGE);
  int* srcP   = ai32(P_NEDGE);
  int* dstP   = ai32(P_NEDGE);
  // state
  float*          X32 = af32((long)P_B * P_NMESH * P_ND);
  unsigned short* XN  = au16((long)P_B * P_NMESH * 320);
  float*          E32 = af32((long)P_B * P_NEDGE * P_ED);
  unsigned short* E16 = au16((long)P_B * P_NEDGE * P_ED);
  // overlay: {ENCIN, RAWPAD} (pre-layers) vs PSPD (per-layer)
  size_t encin_b  = ((size_t)P_B * P_NMESH * 192 * 2 + 255) & ~(size_t)255;
  size_t rawpad_b = ((size_t)P_NEDGE * 64 * 2 + 255) & ~(size_t)255;
  size_t pspd_b   = ((size_t)P_B * P_NMESH * 1024 * 2 + 255) & ~(size_t)255;
  size_t reg1_b   = encin_b + rawpad_b; if (pspd_b > reg1_b) reg1_b = pspd_b;
  char* region1 = (char*)alloc(reg1_b);
  unsigned short* ENCIN  = (unsigned short*)region1;
  unsigned short* RAWPAD = (unsigned short*)(region1 + encin_b);
  unsigned short* PSPD   = (unsigned short*)region1;

  // HBUF: encoder/node hidden (21 MB) + decoder hidden chunk; pick DC by remaining ws
  size_t rem = (ws_size > off + 4096) ? ws_size - off - 4096 : 0;
  size_t hb_full = (size_t)P_B * P_NGRID * 512 * 2;   // 133 MB
  int DC; size_t hb;
  if (rem >= hb_full)          { DC = 1; hb = hb_full; }
  else if (rem >= hb_full / 2) { DC = 2; hb = hb_full / 2; }
  else                         { DC = 4; hb = hb_full / 4; }
  unsigned short* HBUF = (unsigned short*)alloc(hb);

  auto run128 = [&](const GArgs& a, int Npad, int zdim) {
    dim3 grid((a.M + BM - 1) / BM, Npad / 128, zdim);
    gemm_k<128, 64, 64><<<grid, dim3(256), 0, stream>>>(a);
  };
  auto run64 = [&](const GArgs& a, int zdim) {
    dim3 grid((a.M + BM - 1) / BM, 1, zdim);
    gemm_k<64, 32, 64><<<grid, dim3(256), 0, stream>>>(a);
  };
  auto convw = [&](const float* W, unsigned short* Wt, int K, int N, int Kp, int Np,
                   int row_off, long in_lst, long out_lst, int L) {
    long tot = (long)Np * Kp;
    wt_conv<<<dim3((unsigned)((tot + 255) / 256), 1, L), dim3(256), 0, stream>>>(
        W, Wt, K, N, Kp, Np, row_off, in_lst, out_lst);
  };

  // ---- CSR build ----
  hipMemsetAsync(cnt, 0, P_NMESH * 4, stream);
  hipMemsetAsync(cursor, 0, P_NMESH * 4, stream);
  csr_hist<<<dim3(P_NEDGE / 256), dim3(256), 0, stream>>>(dstI, cnt);
  csr_scan<<<dim3(1), dim3(1024), 0, stream>>>(cnt, rowptr);
  csr_scatter<<<dim3(P_NEDGE / 256), dim3(256), 0, stream>>>(dstI, rowptr, cursor, perm);
  csr_permsd<<<dim3(P_NEDGE / 256), dim3(256), 0, stream>>>(perm, srcI, dstI, srcP, dstP);

  // ---- weight conversion ----
  convw(enc_w1, enc_w1t, 163, 512, 192, 512, 0, 163L * 512, 192L * 512, 1);
  convw(enc_w2, enc_w2t, 512, 256, 512, 256, 0, 512L * 256, 512L * 256, 1);
  convw(eme_w1, eme_w1t, 4, 64, 64, 64, 0, 4L * 64, 64L * 64, 1);
  convw(eme_w2, eme_w2t, 64, 64, 64, 64, 0, 64L * 64, 64L * 64, 1);
  convw(pe_w1, pe_w1e_t, 64, 512, 64, 512, 0, 576L * 512, 512L * 64, 16);
  convw(pe_w1, pe_w1sd_t, 256, 512, 256, 512, 64, 576L * 512, 1024L * 256, 16);
  convw(pe_w1, pe_w1sd_t + 512L * 256, 256, 512, 256, 512, 320, 576L * 512, 1024L * 256, 16);
  convw(pe_w2, pe_w2t, 512, 64, 512, 64, 0, 512L * 64, 64L * 512, 16);
  convw(pn_w1, pn_w1t, 320, 512, 320, 512, 0, 320L * 512, 512L * 320, 16);
  convw(pn_w2, pn_w2t, 512, 256, 512, 256, 0, 512L * 256, 256L * 512, 16);
  convw(dec_w1, dec_w1t, 256, 512, 256, 512, 0, 256L * 512, 512L * 256, 1);
  convw(dec_w2, dec_w2t, 512, 78, 512, 128, 0, 512L * 78, 128L * 512, 1);

  // ---- inputs ----
  { long tot = (long)P_B * P_NMESH * 192;
    build_enc_in<<<dim3((unsigned)((tot + 255) / 256)), dim3(256), 0, stream>>>(
        x_current, x_previous, mesh_feats, g2m, ENCIN); }
  { long tot = (long)P_NEDGE * 64;
    build_rawpad<<<dim3((unsigned)((tot + 255) / 256)), dim3(256), 0, stream>>>(
        raw_edge, perm, RAWPAD); }

  // ---- encoder ----
  { GArgs a{}; a.amode = 0; a.A = ENCIN; a.lda = 192; a.M = P_B * P_NMESH; a.K = 192;
    a.Wt = enc_w1t; a.bias = enc_b1; a.Nreal = 512; a.relu = 1;
    a.out16 = HBUF; a.ldo16 = 512; run128(a, 512, 1); }
  { GArgs a{}; a.amode = 0; a.A = HBUF; a.lda = 512; a.M = P_B * P_NMESH; a.K = 512;
    a.Wt = enc_w2t; a.bias = enc_b2; a.Nreal = 256; a.relu = 0;
    a.out32 = X32; a.ldo32 = 256; a.out16 = XN; a.ldo16 = 320; run128(a, 256, 1); }

  // ---- edge embedder (sorted order; dup to batch 1) ----
  { GArgs a{}; a.amode = 0; a.A = RAWPAD; a.lda = 64; a.M = P_NEDGE; a.K = 64;
    a.Wt = eme_w1t; a.bias = eme_b1; a.Nreal = 64; a.relu = 1;
    a.out16 = HBUF; a.ldo16 = 64; run64(a, 1); }
  { GArgs a{}; a.amode = 0; a.A = HBUF; a.lda = 64; a.M = P_NEDGE; a.K = 64;
    a.Wt = eme_w2t; a.bias = eme_b2; a.Nreal = 64; a.relu = 0;
    a.out32 = E32; a.ldo32 = 64; a.dup32 = (long)P_NEDGE * 64;
    a.out16 = E16; a.ldo16 = 64; a.dup16 = (long)P_NEDGE * 64; run64(a, 1); }

  // ---- 16 GNN layers: 5 dispatches each ----
  for (int l = 0; l < P_NLAYERS; ++l) {
    // PSPD = x @ [W1s | W1d]  (N=1024, no bias)
    { GArgs a{}; a.amode = 0; a.A = XN; a.lda = 320; a.M = P_B * P_NMESH; a.K = 256;
      a.Wt = pe_w1sd_t + (long)l * 1024 * 256; a.Nreal = 1024; a.relu = 0;
      a.out16 = PSPD; a.ldo16 = 1024; run128(a, 1024, 1); }
    // fused edge MLP1+MLP2 (+residual, in-place E update)
    { FEArgs f{}; f.E16 = E16; f.E32 = E32; f.PSPD = PSPD;
      f.srcP = srcP; f.dstP = dstP;
      f.W1t = pe_w1e_t + (long)l * 512 * 64;
      f.W2t = pe_w2t + (long)l * 64 * 512;
      f.b1 = pe_b1 + l * 512; f.b2 = pe_b2 + l * 64;
      fused_edge<<<dim3(P_NEDGE / 64, P_B), dim3(256), 0, stream>>>(f); }
    // segment sum -> XN[:,256:320]
    seg_reduce<<<dim3((P_NMESH + 3) / 4, P_B), dim3(256), 0, stream>>>(E32, rowptr, XN);
    // node MLPs
    { GArgs a{}; a.amode = 0; a.A = XN; a.lda = 320; a.M = P_B * P_NMESH; a.K = 320;
      a.Wt = pn_w1t + (long)l * 512 * 320; a.bias = pn_b1 + l * 512; a.Nreal = 512; a.relu = 1;
      a.out16 = HBUF; a.ldo16 = 512; run128(a, 512, 1); }
    { GArgs a{}; a.amode = 0; a.A = HBUF; a.lda = 512; a.M = P_B * P_NMESH; a.K = 512;
      a.Wt = pn_w2t + (long)l * 256 * 512; a.bias = pn_b2 + l * 256; a.Nreal = 256; a.relu = 0;
      a.resid = X32; a.out32 = X32; a.ldo32 = 256; a.out16 = XN; a.ldo16 = 320;
      run128(a, 256, 1); }
  }

  // ---- decoder ----
  const int dcrows = (P_B * P_NGRID) / DC;
  for (int c = 0; c < DC; ++c) {
    int c0 = c * dcrows;
    { GArgs a{}; a.amode = 2; a.A = XN; a.lda = 320;
      a.gidx = m2g; a.gr_off = c0; a.gr_per_b = P_NGRID; a.gsrc_rows_per_b = P_NMESH;
      a.M = dcrows; a.K = 256;
      a.Wt = dec_w1t; a.bias = dec_b1; a.Nreal = 512; a.relu = 1;
      a.out16 = HBUF; a.ldo16 = 512; run128(a, 512, 1); }
    { GArgs a{}; a.amode = 0; a.A = HBUF; a.lda = 512; a.M = dcrows; a.K = 512;
      a.Wt = dec_w2t; a.bias = dec_b2; a.Nreal = 78; a.relu = 0;
      a.out32 = out + (long)c0 * P_V; a.ldo32 = P_V;
      run128(a, 128, 1); }
  }
}

// Round 4
// 5014.799 us; speedup vs baseline: 4.4714x; 1.1153x over previous
//
#include <hip/hip_runtime.h>

// ---------------- problem constants ----------------
#define P_NLAT  181
#define P_NLON  360
#define P_V     78
#define P_NGRID (P_NLAT * P_NLON)   // 65160
#define P_B     2
#define P_NMESH 10242
#define P_NEDGE 163840
#define P_ND    256
#define P_ED    64
#define P_HID   512
#define P_NLAYERS 16

typedef __bf16 bf16x8 __attribute__((ext_vector_type(8)));
typedef unsigned short u16x8 __attribute__((ext_vector_type(8)));
typedef float f32x4 __attribute__((ext_vector_type(4)));

__device__ __forceinline__ unsigned short f2bf(float f) {
  union { float f; unsigned u; } x; x.f = f;
  unsigned r = x.u + 0x7FFFu + ((x.u >> 16) & 1u);   // RNE
  return (unsigned short)(r >> 16);
}
__device__ __forceinline__ float bf2f(unsigned short h) {
  union { unsigned u; float f; } x; x.u = ((unsigned)h) << 16; return x.f;
}

// async global->LDS, 16B per lane; LDS dest is wave-uniform base + lane*16
__device__ __forceinline__ void gl_lds16(const unsigned short* gp, unsigned short* lp) {
  __builtin_amdgcn_global_load_lds(
      (const __attribute__((address_space(1))) unsigned int*)gp,
      (__attribute__((address_space(3))) unsigned int*)lp, 16, 0, 0);
}

// ---------------- generic GEMM (unchanged workhorse) ----------------
struct GArgs {
  int amode;                       // 0=direct, 2=row-index gather
  const unsigned short* A; long lda; long a_bstride;
  const int* gidx; int gr_off; int gr_per_b; int gsrc_rows_per_b;
  int M, K;
  const unsigned short* Wt;        // [Npad][K] bf16
  const float* bias; int Nreal; int relu;
  unsigned short* out16; long ldo16; long o16_bstride; long dup16;
  float* out32; long ldo32; long o32_bstride; long dup32;
  const float* resid; long r_bstride;
};

#define BM 128

template<int BN, int WM, int WN>
__global__ void __launch_bounds__(256) gemm_k(GArgs g) {
  constexpr int MI = WM / 16, NJ = WN / 16;
  constexpr int WPN = BN / WN;
  __shared__ unsigned short As[BM * 64];
  __shared__ unsigned short Bs[BN * 64];

  const int tid  = threadIdx.x;
  const int lane = tid & 63, wid = tid >> 6;
  const int wm = (wid / WPN) * WM, wn = (wid % WPN) * WN;
  const int bm = blockIdx.x * BM;
  const int bn = blockIdx.y * BN;
  const int z  = blockIdx.z;

  const unsigned short* Ad = g.A + (long)z * g.a_bstride;

  f32x4 acc[MI][NJ];
  #pragma unroll
  for (int i = 0; i < MI; ++i)
    #pragma unroll
    for (int j = 0; j < NJ; ++j) { f32x4 zv = {0.f, 0.f, 0.f, 0.f}; acc[i][j] = zv; }

  const int nKt = g.K >> 6;
  for (int kt = 0; kt < nKt; ++kt) {
    const int k0 = kt << 6;
    #pragma unroll
    for (int it = 0; it < (BM * 8) / 256; ++it) {
      int v = tid + it * 256;
      int r = v >> 3, j = v & 7;
      int row = bm + r; if (row >= g.M) row = g.M - 1;
      int kk = k0 + ((j ^ (r & 7)) << 3);
      const unsigned short* s;
      if (g.amode == 0) {
        s = Ad + (long)row * g.lda + kk;
      } else {
        int gr = g.gr_off + row;
        int b = gr / g.gr_per_b, loc = gr - b * g.gr_per_b;
        s = g.A + ((long)b * g.gsrc_rows_per_b + g.gidx[loc]) * g.lda + kk;
      }
      gl_lds16(s, &As[v << 3]);
    }
    #pragma unroll
    for (int it = 0; it < (BN * 8) / 256; ++it) {
      int v = tid + it * 256;
      int n = v >> 3, j = v & 7;
      gl_lds16(g.Wt + (long)(bn + n) * g.K + k0 + ((j ^ (n & 7)) << 3), &Bs[v << 3]);
    }
    __syncthreads();
    #pragma unroll
    for (int ko = 0; ko < 2; ++ko) {
      bf16x8 af[MI], bfr[NJ];
      #pragma unroll
      for (int i = 0; i < MI; ++i) {
        int ar = wm + i * 16 + (lane & 15);
        int ch = ((ko * 4 + (lane >> 4)) ^ (ar & 7)) << 3;
        u16x8 t = *(const u16x8*)&As[ar * 64 + ch];
        af[i] = __builtin_bit_cast(bf16x8, t);
      }
      #pragma unroll
      for (int j = 0; j < NJ; ++j) {
        int br = wn + j * 16 + (lane & 15);
        int ch = ((ko * 4 + (lane >> 4)) ^ (br & 7)) << 3;
        u16x8 t = *(const u16x8*)&Bs[br * 64 + ch];
        bfr[j] = __builtin_bit_cast(bf16x8, t);
      }
      #pragma unroll
      for (int i = 0; i < MI; ++i)
        #pragma unroll
        for (int j = 0; j < NJ; ++j)
          acc[i][j] = __builtin_amdgcn_mfma_f32_16x16x32_bf16(af[i], bfr[j], acc[i][j], 0, 0, 0);
    }
    __syncthreads();
  }

  unsigned short* o16 = g.out16 ? g.out16 + (long)z * g.o16_bstride : (unsigned short*)0;
  float* o32 = g.out32 ? g.out32 + (long)z * g.o32_bstride : (float*)0;
  const float* res = g.resid ? g.resid + (long)z * g.r_bstride : (const float*)0;
  const int q = lane >> 4, cc = lane & 15;
  #pragma unroll
  for (int i = 0; i < MI; ++i) {
    #pragma unroll
    for (int r = 0; r < 4; ++r) {
      int row = bm + wm + i * 16 + q * 4 + r;
      if (row >= g.M) continue;
      const float* rr = res ? res + (long)row * g.ldo32 : (const float*)0;
      #pragma unroll
      for (int j = 0; j < NJ; ++j) {
        int col = bn + wn + j * 16 + cc;
        if (col >= g.Nreal) continue;
        float v = acc[i][j][r];
        if (g.bias) v += g.bias[col];
        if (rr) v += rr[col];
        if (g.relu && v < 0.f) v = 0.f;
        if (o32) {
          long idx = (long)row * g.ldo32 + col;
          o32[idx] = v; if (g.dup32) o32[idx + g.dup32] = v;
        }
        if (o16) {
          long idx = (long)row * g.ldo16 + col;
          unsigned short h = f2bf(v);
          o16[idx] = h; if (g.dup16) o16[idx + g.dup16] = h;
        }
      }
    }
  }
}

// ---------------- fused edge layer v2: 33.8KB LDS -> 4 blocks/CU ----------------
// E' = E + MLP2(relu(E@W1e + Ps[src] + Pd[dst] + b1)), hidden chunked by 64 (8 chunks)
struct FEArgs {
  unsigned short* E16;             // in/out, dst-sorted, per-batch stride NEDGE*64
  float* E32;                      // in/out residual master
  const unsigned short* PSPD;      // [B*NMESH][1024]: cols 0..511 = Ps, 512..1023 = Pd
  const int* srcP; const int* dstP;
  const unsigned short* W1t;       // [512][64]
  const unsigned short* W2t;       // [64][512]
  const float* b1; const float* b2;
};

__global__ void __launch_bounds__(256, 4) fused_edge(FEArgs g) {
  __shared__ unsigned short As[64 * 64];   // e tile, chunk-swizzled            8 KB
  __shared__ float HS[64 * 68];            // fp32 h spill (stride 68);        17 KB
                                           // bf16 overlay stride 64, swizzled
  __shared__ unsigned short WS[64 * 64];   // W1c / W2c chunk, swizzled         8 KB

  const int tid = threadIdx.x, lane = tid & 63, wid = tid >> 6;
  const int q = lane >> 4, cc = lane & 15;
  const int z = blockIdx.y;
  const long gr0 = (long)blockIdx.x * 64;
  const long EB = (long)P_NEDGE * 64;
  unsigned short* E16z = g.E16 + z * EB;
  float* E32z = g.E32 + z * EB;
  const int moff = z * P_NMESH;
  unsigned short* HSb = (unsigned short*)HS;
  const int wm = wid * 16;                  // wave row-tile (both GEMMs)

  // stage e tile (async; first loop barrier covers it)
  #pragma unroll
  for (int it = 0; it < 2; ++it) {
    int v = tid + it * 256;
    int r = v >> 3, j = v & 7;
    gl_lds16(E16z + (gr0 + r) * 64 + ((j ^ (r & 7)) << 3), &As[v << 3]);
  }

  f32x4 acc2[4];
  #pragma unroll
  for (int j = 0; j < 4; ++j) { f32x4 zv = {0.f, 0.f, 0.f, 0.f}; acc2[j] = zv; }

  for (int hc = 0; hc < 8; ++hc) {
    // stage W1 chunk rows [hc*64, +64) of W1t[512][64]
    #pragma unroll
    for (int it = 0; it < 2; ++it) {
      int v = tid + it * 256;
      int n = v >> 3, j = v & 7;
      gl_lds16(g.W1t + (long)(hc * 64 + n) * 64 + ((j ^ (n & 7)) << 3), &WS[v << 3]);
    }
    __syncthreads();   // (A) W1c + (iter0) As resident

    // GEMM1: h(64 x 64) = e @ W1c, K=64
    f32x4 acc1[4];
    #pragma unroll
    for (int j = 0; j < 4; ++j) { f32x4 zv = {0.f, 0.f, 0.f, 0.f}; acc1[j] = zv; }
    #pragma unroll
    for (int ko = 0; ko < 2; ++ko) {
      int ar = wm + cc;
      u16x8 ta = *(const u16x8*)&As[ar * 64 + (((ko * 4 + q) ^ (ar & 7)) << 3)];
      bf16x8 af = __builtin_bit_cast(bf16x8, ta);
      #pragma unroll
      for (int j = 0; j < 4; ++j) {
        int n = j * 16 + cc;
        u16x8 tb = *(const u16x8*)&WS[n * 64 + (((ko * 4 + q) ^ (n & 7)) << 3)];
        bf16x8 bf = __builtin_bit_cast(bf16x8, tb);
        acc1[j] = __builtin_amdgcn_mfma_f32_16x16x32_bf16(af, bf, acc1[j], 0, 0, 0);
      }
    }
    // spill raw fp32 h (stride 68 -> 2-way max)
    #pragma unroll
    for (int j = 0; j < 4; ++j)
      #pragma unroll
      for (int r = 0; r < 4; ++r)
        HS[(wm + q * 4 + r) * 68 + j * 16 + cc] = acc1[j][r];
    __syncthreads();   // (B) spill visible; W1c reads done

    // stage W2 chunk cols [hc*64, +64) of W2t[64][512] (async, lands by next barrier)
    #pragma unroll
    for (int it = 0; it < 2; ++it) {
      int v = tid + it * 256;
      int n = v >> 3, j = v & 7;
      gl_lds16(g.W2t + (long)n * 512 + hc * 64 + ((j ^ (n & 7)) << 3), &WS[v << 3]);
    }
    // pass2: regs <- relu(h + b1 + Ps[src] + Pd[dst])
    float hv[2][8];
    #pragma unroll
    for (int it = 0; it < 2; ++it) {
      int v = tid + it * 256;
      int r = v >> 3, c8 = (v & 7) << 3;
      long grow = gr0 + r;
      const unsigned short* ps = g.PSPD + (long)(moff + g.srcP[grow]) * 1024 + hc * 64 + c8;
      const unsigned short* pd = g.PSPD + (long)(moff + g.dstP[grow]) * 1024 + 512 + hc * 64 + c8;
      u16x8 psv = *(const u16x8*)ps;
      u16x8 pdv = *(const u16x8*)pd;
      f32x4 ha = *(const f32x4*)&HS[r * 68 + c8];
      f32x4 hb = *(const f32x4*)&HS[r * 68 + c8 + 4];
      const float* b1p = g.b1 + hc * 64 + c8;
      #pragma unroll
      for (int e = 0; e < 8; ++e) {
        float x = (e < 4 ? ha[e] : hb[e - 4]) + b1p[e] + bf2f(psv[e]) + bf2f(pdv[e]);
        hv[it][e] = x < 0.f ? 0.f : x;
      }
    }
    __syncthreads();   // (C) all fp32 reads done; W2c resident

    // write bf16 h overlay into HS (stride 64, chunk-swizzled, 16B aligned)
    #pragma unroll
    for (int it = 0; it < 2; ++it) {
      int v = tid + it * 256;
      int r = v >> 3, j = v & 7;
      u16x8 outv;
      #pragma unroll
      for (int e = 0; e < 8; ++e) outv[e] = f2bf(hv[it][e]);
      *(u16x8*)&HSb[r * 64 + ((j ^ (r & 7)) << 3)] = outv;
    }
    __syncthreads();   // (D) bf16 h ready

    // GEMM2: acc2 += h_chunk(64x64) @ W2c(64x64)
    #pragma unroll
    for (int ko = 0; ko < 2; ++ko) {
      int ar = wm + cc;
      u16x8 ta = *(const u16x8*)&HSb[ar * 64 + (((ko * 4 + q) ^ (ar & 7)) << 3)];
      bf16x8 af = __builtin_bit_cast(bf16x8, ta);
      #pragma unroll
      for (int j = 0; j < 4; ++j) {
        int n = j * 16 + cc;
        u16x8 tb = *(const u16x8*)&WS[n * 64 + (((ko * 4 + q) ^ (n & 7)) << 3)];
        bf16x8 bf = __builtin_bit_cast(bf16x8, tb);
        acc2[j] = __builtin_amdgcn_mfma_f32_16x16x32_bf16(af, bf, acc2[j], 0, 0, 0);
      }
    }
    __syncthreads();   // (E) HS/WS free for next chunk
  }

  // epilogue: residual update (block owns its 64 rows exclusively)
  #pragma unroll
  for (int j = 0; j < 4; ++j) {
    #pragma unroll
    for (int r = 0; r < 4; ++r) {
      int row = wm + q * 4 + r;
      int col = j * 16 + cc;
      long idx = (gr0 + row) * 64 + col;
      float v = acc2[j][r] + g.b2[col] + E32z[idx];
      E32z[idx] = v;
      E16z[idx] = f2bf(v);
    }
  }
}

// ---------------- prep kernels ----------------
__global__ void wt_conv(const float* W, unsigned short* Wt, int K, int N, int Kpad, int Npad,
                        int row_off, long in_lstride, long out_lstride) {
  long t = (long)blockIdx.x * 256 + threadIdx.x;
  long tot = (long)Npad * Kpad;
  if (t >= tot) return;
  int n = (int)(t / Kpad), k = (int)(t - (long)n * Kpad);
  const float* Wl = W + (long)blockIdx.z * in_lstride + (long)row_off * N;
  float v = (n < N && k < K) ? Wl[(long)k * N + n] : 0.f;
  Wt[(long)blockIdx.z * out_lstride + t] = f2bf(v);
}

__global__ void build_enc_in(const float* xc, const float* xp, const float* mesh,
                             const int* g2m, unsigned short* out) {
  long t = (long)blockIdx.x * 256 + threadIdx.x;
  const long tot = (long)P_B * P_NMESH * 192;
  if (t >= tot) return;
  int k = (int)(t % 192); long r = t / 192;
  int m = (int)(r % P_NMESH); int b = (int)(r / P_NMESH);
  float v = 0.f;
  if (k < P_V)              v = xc[((long)b * P_NGRID + g2m[m]) * P_V + k];
  else if (k < 2 * P_V)     v = xp[((long)b * P_NGRID + g2m[m]) * P_V + (k - P_V)];
  else if (k < 2 * P_V + 7) v = mesh[m * 7 + (k - 2 * P_V)];
  out[t] = f2bf(v);
}

__global__ void build_rawpad(const float* raw, const int* perm, unsigned short* out) {
  long t = (long)blockIdx.x * 256 + threadIdx.x;
  const long tot = (long)P_NEDGE * 64;
  if (t >= tot) return;
  int k = (int)(t & 63); long r = t >> 6;
  int e = perm[r];
  out[t] = f2bf(k < 4 ? raw[(long)e * 4 + k] : 0.f);
}

// ---------------- CSR build (counting sort by dst) ----------------
__global__ void csr_hist(const int* dst, int* cnt) {
  int e = blockIdx.x * 256 + threadIdx.x;
  if (e < P_NEDGE) atomicAdd(&cnt[dst[e]], 1);
}
__global__ void csr_scan(const int* cnt, int* rowptr) {
  __shared__ int part[1024];
  int t = threadIdx.x;
  const int C = (P_NMESH + 1023) / 1024;
  int base = t * C, s = 0;
  for (int i = 0; i < C; ++i) { int idx = base + i; if (idx < P_NMESH) s += cnt[idx]; }
  part[t] = s; __syncthreads();
  for (int ofs = 1; ofs < 1024; ofs <<= 1) {
    int v = (t >= ofs) ? part[t - ofs] : 0;
    __syncthreads();
    part[t] += v;
    __syncthreads();
  }
  int excl = (t == 0) ? 0 : part[t - 1];
  for (int i = 0; i < C; ++i) {
    int idx = base + i;
    if (idx < P_NMESH) { rowptr[idx] = excl; excl += cnt[idx]; }
  }
  if (t == 1023) rowptr[P_NMESH] = excl;
}
__global__ void csr_scatter(const int* dst, const int* rowptr, int* cursor, int* perm) {
  int e = blockIdx.x * 256 + threadIdx.x;
  if (e < P_NEDGE) {
    int d = dst[e];
    int pos = atomicAdd(&cursor[d], 1);
    perm[rowptr[d] + pos] = e;
  }
}
__global__ void csr_permsd(const int* perm, const int* src, const int* dst, int* srcP, int* dstP) {
  int i = blockIdx.x * 256 + threadIdx.x;
  if (i < P_NEDGE) { int p = perm[i]; srcP[i] = src[p]; dstP[i] = dst[p]; }
}

// contiguous segmented sum over dst-sorted E32 -> bf16 into XN[:, 256:320]
__global__ void seg_reduce(const float* E32, const int* rowptr, unsigned short* XN) {
  int node = blockIdx.x * 4 + (threadIdx.x >> 6);
  int c = threadIdx.x & 63;
  int b = blockIdx.y;
  if (node >= P_NMESH) return;
  int r0 = rowptr[node], r1 = rowptr[node + 1];
  const float* base = E32 + (long)b * P_NEDGE * 64;
  float s = 0.f;
  for (int r = r0; r < r1; ++r) s += base[(long)r * 64 + c];
  XN[((long)b * P_NMESH + node) * 320 + 256 + c] = f2bf(s);
}

// ---------------- host launch ----------------
extern "C" void kernel_launch(void* const* d_in, const int* in_sizes, int n_in,
                              void* d_out, int out_size, void* d_ws, size_t ws_size,
                              hipStream_t stream) {
  (void)in_sizes; (void)n_in; (void)out_size;
  const float* x_current  = (const float*)d_in[0];
  const float* x_previous = (const float*)d_in[1];
  const float* mesh_feats = (const float*)d_in[2];
  const float* raw_edge   = (const float*)d_in[3];
  const int*   edge_index = (const int*)d_in[4];
  const int*   g2m        = (const int*)d_in[5];
  const int*   m2g        = (const int*)d_in[6];
  const float* enc_w1 = (const float*)d_in[7];
  const float* enc_b1 = (const float*)d_in[8];
  const float* enc_w2 = (const float*)d_in[9];
  const float* enc_b2 = (const float*)d_in[10];
  const float* eme_w1 = (const float*)d_in[11];
  const float* eme_b1 = (const float*)d_in[12];
  const float* eme_w2 = (const float*)d_in[13];
  const float* eme_b2 = (const float*)d_in[14];
  const float* pe_w1 = (const float*)d_in[15];
  const float* pe_b1 = (const float*)d_in[16];
  const float* pe_w2 = (const float*)d_in[17];
  const float* pe_b2 = (const float*)d_in[18];
  const float* pn_w1 = (const float*)d_in[19];
  const float* pn_b1 = (const float*)d_in[20];
  const float* pn_w2 = (const float*)d_in[21];
  const float* pn_b2 = (const float*)d_in[22];
  const float* dec_w1 = (const float*)d_in[23];
  const float* dec_b1 = (const float*)d_in[24];
  const float* dec_w2 = (const float*)d_in[25];
  const float* dec_b2 = (const float*)d_in[26];
  const int* srcI = edge_index;
  const int* dstI = edge_index + P_NEDGE;
  float* out = (float*)d_out;

  char* wsb = (char*)d_ws; size_t off = 0;
  auto alloc = [&](size_t bytes) -> void* {
    off = (off + 255) & ~(size_t)255;
    void* p = wsb + off; off += bytes; return p;
  };
  auto au16 = [&](long n) { return (unsigned short*)alloc((size_t)n * 2); };
  auto af32 = [&](long n) { return (float*)alloc((size_t)n * 4); };
  auto ai32 = [&](long n) { return (int*)alloc((size_t)n * 4); };

  // weights (bf16, transposed [N][K])
  unsigned short* enc_w1t   = au16(512L * 192);
  unsigned short* enc_w2t   = au16(256L * 512);
  unsigned short* eme_w1t   = au16(64L * 64);
  unsigned short* eme_w2t   = au16(64L * 64);
  unsigned short* pe_w1e_t  = au16(16L * 512 * 64);
  unsigned short* pe_w1sd_t = au16(16L * 1024 * 256);   // [1024][256]: s rows 0..511, d rows 512..1023
  unsigned short* pe_w2t    = au16(16L * 64 * 512);
  unsigned short* pn_w1t    = au16(16L * 512 * 320);
  unsigned short* pn_w2t    = au16(16L * 256 * 512);
  unsigned short* dec_w1t   = au16(512L * 256);
  unsigned short* dec_w2t   = au16(128L * 512);
  // CSR
  int* cnt    = ai32(P_NMESH);
  int* cursor = ai32(P_NMESH);
  int* rowptr = ai32(P_NMESH + 1);
  int* perm   = ai32(P_NEDGE);
  int* srcP   = ai32(P_NEDGE);
  int* dstP   = ai32(P_NEDGE);
  // state
  float*          X32 = af32((long)P_B * P_NMESH * P_ND);
  unsigned short* XN  = au16((long)P_B * P_NMESH * 320);
  float*          E32 = af32((long)P_B * P_NEDGE * P_ED);
  unsigned short* E16 = au16((long)P_B * P_NEDGE * P_ED);
  // overlay: {ENCIN, RAWPAD} (pre-layers) vs PSPD (per-layer)
  size_t encin_b  = ((size_t)P_B * P_NMESH * 192 * 2 + 255) & ~(size_t)255;
  size_t rawpad_b = ((size_t)P_NEDGE * 64 * 2 + 255) & ~(size_t)255;
  size_t pspd_b   = ((size_t)P_B * P_NMESH * 1024 * 2 + 255) & ~(size_t)255;
  size_t reg1_b   = encin_b + rawpad_b; if (pspd_b > reg1_b) reg1_b = pspd_b;
  char* region1 = (char*)alloc(reg1_b);
  unsigned short* ENCIN  = (unsigned short*)region1;
  unsigned short* RAWPAD = (unsigned short*)(region1 + encin_b);
  unsigned short* PSPD   = (unsigned short*)region1;

  // HBUF: encoder/node hidden + decoder hidden chunk; pick DC by remaining ws
  size_t rem = (ws_size > off + 4096) ? ws_size - off - 4096 : 0;
  size_t hb_full = (size_t)P_B * P_NGRID * 512 * 2;   // 133 MB
  int DC; size_t hb;
  if (rem >= hb_full)          { DC = 1; hb = hb_full; }
  else if (rem >= hb_full / 2) { DC = 2; hb = hb_full / 2; }
  else                         { DC = 4; hb = hb_full / 4; }
  unsigned short* HBUF = (unsigned short*)alloc(hb);

  auto run128 = [&](const GArgs& a, int Npad, int zdim) {
    dim3 grid((a.M + BM - 1) / BM, Npad / 128, zdim);
    gemm_k<128, 64, 64><<<grid, dim3(256), 0, stream>>>(a);
  };
  auto run64 = [&](const GArgs& a, int zdim) {
    dim3 grid((a.M + BM - 1) / BM, 1, zdim);
    gemm_k<64, 32, 64><<<grid, dim3(256), 0, stream>>>(a);
  };
  auto convw = [&](const float* W, unsigned short* Wt, int K, int N, int Kp, int Np,
                   int row_off, long in_lst, long out_lst, int L) {
    long tot = (long)Np * Kp;
    wt_conv<<<dim3((unsigned)((tot + 255) / 256), 1, L), dim3(256), 0, stream>>>(
        W, Wt, K, N, Kp, Np, row_off, in_lst, out_lst);
  };

  // ---- CSR build ----
  hipMemsetAsync(cnt, 0, P_NMESH * 4, stream);
  hipMemsetAsync(cursor, 0, P_NMESH * 4, stream);
  csr_hist<<<dim3(P_NEDGE / 256), dim3(256), 0, stream>>>(dstI, cnt);
  csr_scan<<<dim3(1), dim3(1024), 0, stream>>>(cnt, rowptr);
  csr_scatter<<<dim3(P_NEDGE / 256), dim3(256), 0, stream>>>(dstI, rowptr, cursor, perm);
  csr_permsd<<<dim3(P_NEDGE / 256), dim3(256), 0, stream>>>(perm, srcI, dstI, srcP, dstP);

  // ---- weight conversion ----
  convw(enc_w1, enc_w1t, 163, 512, 192, 512, 0, 163L * 512, 192L * 512, 1);
  convw(enc_w2, enc_w2t, 512, 256, 512, 256, 0, 512L * 256, 512L * 256, 1);
  convw(eme_w1, eme_w1t, 4, 64, 64, 64, 0, 4L * 64, 64L * 64, 1);
  convw(eme_w2, eme_w2t, 64, 64, 64, 64, 0, 64L * 64, 64L * 64, 1);
  convw(pe_w1, pe_w1e_t, 64, 512, 64, 512, 0, 576L * 512, 512L * 64, 16);
  convw(pe_w1, pe_w1sd_t, 256, 512, 256, 512, 64, 576L * 512, 1024L * 256, 16);
  convw(pe_w1, pe_w1sd_t + 512L * 256, 256, 512, 256, 512, 320, 576L * 512, 1024L * 256, 16);
  convw(pe_w2, pe_w2t, 512, 64, 512, 64, 0, 512L * 64, 64L * 512, 16);
  convw(pn_w1, pn_w1t, 320, 512, 320, 512, 0, 320L * 512, 512L * 320, 16);
  convw(pn_w2, pn_w2t, 512, 256, 512, 256, 0, 512L * 256, 256L * 512, 16);
  convw(dec_w1, dec_w1t, 256, 512, 256, 512, 0, 256L * 512, 512L * 256, 1);
  convw(dec_w2, dec_w2t, 512, 78, 512, 128, 0, 512L * 78, 128L * 512, 1);

  // ---- inputs ----
  { long tot = (long)P_B * P_NMESH * 192;
    build_enc_in<<<dim3((unsigned)((tot + 255) / 256)), dim3(256), 0, stream>>>(
        x_current, x_previous, mesh_feats, g2m, ENCIN); }
  { long tot = (long)P_NEDGE * 64;
    build_rawpad<<<dim3((unsigned)((tot + 255) / 256)), dim3(256), 0, stream>>>(
        raw_edge, perm, RAWPAD); }

  // ---- encoder ----
  { GArgs a{}; a.amode = 0; a.A = ENCIN; a.lda = 192; a.M = P_B * P_NMESH; a.K = 192;
    a.Wt = enc_w1t; a.bias = enc_b1; a.Nreal = 512; a.relu = 1;
    a.out16 = HBUF; a.ldo16 = 512; run128(a, 512, 1); }
  { GArgs a{}; a.amode = 0; a.A = HBUF; a.lda = 512; a.M = P_B * P_NMESH; a.K = 512;
    a.Wt = enc_w2t; a.bias = enc_b2; a.Nreal = 256; a.relu = 0;
    a.out32 = X32; a.ldo32 = 256; a.out16 = XN; a.ldo16 = 320; run128(a, 256, 1); }

  // ---- edge embedder (sorted order; dup to batch 1) ----
  { GArgs a{}; a.amode = 0; a.A = RAWPAD; a.lda = 64; a.M = P_NEDGE; a.K = 64;
    a.Wt = eme_w1t; a.bias = eme_b1; a.Nreal = 64; a.relu = 1;
    a.out16 = HBUF; a.ldo16 = 64; run64(a, 1); }
  { GArgs a{}; a.amode = 0; a.A = HBUF; a.lda = 64; a.M = P_NEDGE; a.K = 64;
    a.Wt = eme_w2t; a.bias = eme_b2; a.Nreal = 64; a.relu = 0;
    a.out32 = E32; a.ldo32 = 64; a.dup32 = (long)P_NEDGE * 64;
    a.out16 = E16; a.ldo16 = 64; a.dup16 = (long)P_NEDGE * 64; run64(a, 1); }

  // ---- 16 GNN layers: 5 dispatches each ----
  for (int l = 0; l < P_NLAYERS; ++l) {
    // PSPD = x @ [W1s | W1d]  (N=1024, no bias)
    { GArgs a{}; a.amode = 0; a.A = XN; a.lda = 320; a.M = P_B * P_NMESH; a.K = 256;
      a.Wt = pe_w1sd_t + (long)l * 1024 * 256; a.Nreal = 1024; a.relu = 0;
      a.out16 = PSPD; a.ldo16 = 1024; run128(a, 1024, 1); }
    // fused edge MLP1+MLP2 (+residual, in-place E update)
    { FEArgs f{}; f.E16 = E16; f.E32 = E32; f.PSPD = PSPD;
      f.srcP = srcP; f.dstP = dstP;
      f.W1t = pe_w1e_t + (long)l * 512 * 64;
      f.W2t = pe_w2t + (long)l * 64 * 512;
      f.b1 = pe_b1 + l * 512; f.b2 = pe_b2 + l * 64;
      fused_edge<<<dim3(P_NEDGE / 64, P_B), dim3(256), 0, stream>>>(f); }
    // segment sum -> XN[:,256:320]
    seg_reduce<<<dim3((P_NMESH + 3) / 4, P_B), dim3(256), 0, stream>>>(E32, rowptr, XN);
    // node MLPs
    { GArgs a{}; a.amode = 0; a.A = XN; a.lda = 320; a.M = P_B * P_NMESH; a.K = 320;
      a.Wt = pn_w1t + (long)l * 512 * 320; a.bias = pn_b1 + l * 512; a.Nreal = 512; a.relu = 1;
      a.out16 = HBUF; a.ldo16 = 512; run128(a, 512, 1); }
    { GArgs a{}; a.amode = 0; a.A = HBUF; a.lda = 512; a.M = P_B * P_NMESH; a.K = 512;
      a.Wt = pn_w2t + (long)l * 256 * 512; a.bias = pn_b2 + l * 256; a.Nreal = 256; a.relu = 0;
      a.resid = X32; a.out32 = X32; a.ldo32 = 256; a.out16 = XN; a.ldo16 = 320;
      run128(a, 256, 1); }
  }

  // ---- decoder ----
  const int dcrows = (P_B * P_NGRID) / DC;
  for (int c = 0; c < DC; ++c) {
    int c0 = c * dcrows;
    { GArgs a{}; a.amode = 2; a.A = XN; a.lda = 320;
      a.gidx = m2g; a.gr_off = c0; a.gr_per_b = P_NGRID; a.gsrc_rows_per_b = P_NMESH;
      a.M = dcrows; a.K = 256;
      a.Wt = dec_w1t; a.bias = dec_b1; a.Nreal = 512; a.relu = 1;
      a.out16 = HBUF; a.ldo16 = 512; run128(a, 512, 1); }
    { GArgs a{}; a.amode = 0; a.A = HBUF; a.lda = 512; a.M = dcrows; a.K = 512;
      a.Wt = dec_w2t; a.bias = dec_b2; a.Nreal = 78; a.relu = 0;
      a.out32 = out + (long)c0 * P_V; a.ldo32 = P_V;
      run128(a, 128, 1); }
  }
}